// Round 7
// baseline (533.406 us; speedup 1.0000x reference)
//
#include <hip/hip_runtime.h>
#include <hip/hip_fp16.h>

#define F_IN 35
#define F_OUT 5
#define HID 100
#define BSH 8              // 256 node-ids per bucket
#define BMSK 255
#define MAXB 512           // max buckets (requires N <= 131072)

// 15-bit relative float for w in (0,1]: 4-bit exp, 11-bit mantissa.
__device__ __forceinline__ unsigned qenc(float w) {
  unsigned b = __float_as_uint(w);
  int e = 127 - (int)((b >> 23) & 0xFF);
  unsigned m = (b >> 12) & 0x7FFu;
  if (e < 0) { e = 0; m = 0; }
  if (e > 15) { e = 15; m = 0; }
  return ((unsigned)e << 11) | m;
}
__device__ __forceinline__ float qdec(unsigned q) {
  return __uint_as_float(((127u - (q >> 11)) << 23) | ((q & 0x7FFu) << 12));
}

__device__ __forceinline__ float2 uph2(unsigned u) {
  __half2 h = *reinterpret_cast<const __half2*>(&u);
  return __half22float2(h);
}
__device__ __forceinline__ unsigned pkh2(float a, float b) {
  __half2 h = __floats2half2_rn(a, b);
  return *reinterpret_cast<const unsigned*>(&h);
}

// Non-temporal (nt, LRU-evict-first) access helpers: keep streaming traffic
// from evicting the L2-resident gather arrays.
__device__ __forceinline__ int ntli(const int* p) {
  return __builtin_nontemporal_load(p);
}
__device__ __forceinline__ float ntlf(const float* p) {
  return __builtin_nontemporal_load(p);
}
__device__ __forceinline__ float ntlh(const __half* p) {
  unsigned short u = __builtin_nontemporal_load((const unsigned short*)p);
  __half h = *reinterpret_cast<__half*>(&u);
  return __half2float(h);
}
__device__ __forceinline__ void ntsf(float* p, float v) {
  __builtin_nontemporal_store(v, p);
}
__device__ __forceinline__ void ntsh(__half* p, float v) {
  __half h = __float2half(v);
  unsigned short u = *reinterpret_cast<unsigned short*>(&h);
  __builtin_nontemporal_store(u, (unsigned short*)p);
}

// ---------------------------------------------------------------------------
// Weight prep.
// WpackA [40x50]: 0-4 Dz, 5-9 Dr, 10-14 Fz1, 15-19 Fr1, 20-24 Fz2, 25-29 Fr2,
//                 30-34 Bz1, 35-39 Br1, 40-44 Bz2, 45-49 Br2
// WpackC [40x25]: 0-4 Dh, 5-9 Fh1, 10-14 Fh2, 15-19 Bh1, 20-24 Bh2
// ---------------------------------------------------------------------------
__global__ __launch_bounds__(256) void prep_weights(
    const float* __restrict__ Wz, const float* __restrict__ Wr,
    const float* __restrict__ Wh,
    float* __restrict__ WpackA, float* __restrict__ WpackC) {
  int t = blockIdx.x * blockDim.x + threadIdx.x;
  if (t < 40 * 50) {
    int i = t / 50, c = t % 50;
    auto W = [&](const float* Wp, int d, int k, int o) {
      return Wp[((d * 3 + k) * 40 + i) * 5 + o];
    };
    float v;
    if (c < 5)       v = W(Wz,0,0,c)    + W(Wz,1,0,c)    - W(Wz,0,2,c)    - W(Wz,1,2,c);
    else if (c < 10) v = W(Wr,0,0,c-5)  + W(Wr,1,0,c-5)  - W(Wr,0,2,c-5)  - W(Wr,1,2,c-5);
    else if (c < 15) v = W(Wz,0,1,c-10);
    else if (c < 20) v = W(Wr,0,1,c-15);
    else if (c < 25) v = W(Wz,0,2,c-20);
    else if (c < 30) v = W(Wr,0,2,c-25);
    else if (c < 35) v = W(Wz,1,1,c-30);
    else if (c < 40) v = W(Wr,1,1,c-35);
    else if (c < 45) v = W(Wz,1,2,c-40);
    else             v = W(Wr,1,2,c-45);
    WpackA[i * 50 + c] = v;
  }
  if (t < 40 * 25) {
    int i = t / 25, c = t % 25;
    auto W = [&](const float* Wp, int d, int k, int o) {
      return Wp[((d * 3 + k) * 40 + i) * 5 + o];
    };
    float v;
    if (c < 5)       v = W(Wh,0,0,c)    + W(Wh,1,0,c)    - W(Wh,0,2,c)    - W(Wh,1,2,c);
    else if (c < 10) v = W(Wh,0,1,c-5);
    else if (c < 15) v = W(Wh,0,2,c-10);
    else if (c < 20) v = W(Wh,1,1,c-15);
    else             v = W(Wh,1,2,c-20);
    WpackC[i * 25 + c] = v;
  }
}

// ---------------------------------------------------------------------------
// Build 1: bucket histograms (LDS pre-aggregated).
// ---------------------------------------------------------------------------
__global__ __launch_bounds__(256) void hist_kernel(
    const int* __restrict__ ei, int* __restrict__ bcnt_f,
    int* __restrict__ bcnt_b, int E) {
  __shared__ int h[2 * MAXB];
  for (int j = threadIdx.x; j < 2 * MAXB; j += blockDim.x) h[j] = 0;
  __syncthreads();
  for (int e = blockIdx.x * blockDim.x + threadIdx.x; e < E;
       e += gridDim.x * blockDim.x) {
    int s = ntli(ei + e), d = ntli(ei + E + e);
    atomicAdd(&h[d >> BSH], 1);
    atomicAdd(&h[MAXB + (s >> BSH)], 1);
  }
  __syncthreads();
  for (int j = threadIdx.x; j < 2 * MAXB; j += blockDim.x) {
    int v = h[j];
    if (v) {
      if (j < MAXB) atomicAdd(&bcnt_f[j], v);
      else          atomicAdd(&bcnt_b[j - MAXB], v);
    }
  }
}

// ---------------------------------------------------------------------------
// Build 2: bucket exclusive scan -> bases + cursors; rs[N]=E sentinels.
// ---------------------------------------------------------------------------
__global__ __launch_bounds__(512) void scanb_kernel(
    const int* __restrict__ bcnt_f, const int* __restrict__ bcnt_b,
    int* __restrict__ bbase_f, int* __restrict__ bbase_b,
    int* __restrict__ bcur_f, int* __restrict__ bcur_b,
    int* __restrict__ rs_f, int* __restrict__ rs_b,
    int nbuck, int N, int E) {
  __shared__ int s0[MAXB], s1[MAXB];
  int t = threadIdx.x;
  s0[t] = (t < nbuck) ? bcnt_f[t] : 0;
  s1[t] = (t < nbuck) ? bcnt_b[t] : 0;
  __syncthreads();
  for (int off = 1; off < MAXB; off <<= 1) {
    int a = (t >= off) ? s0[t - off] : 0;
    int b = (t >= off) ? s1[t - off] : 0;
    __syncthreads();
    s0[t] += a; s1[t] += b;
    __syncthreads();
  }
  bbase_f[t + 1] = s0[t];
  bbase_b[t + 1] = s1[t];
  bcur_f[t] = t ? s0[t - 1] : 0;
  bcur_b[t] = t ? s1[t - 1] : 0;
  if (t == 0) { bbase_f[0] = 0; bbase_b[0] = 0; rs_f[N] = E; rs_b[N] = E; }
}

// ---------------------------------------------------------------------------
// Build 3: bin edges into compact bucket regions. Item: other|keylow<<17, w.
// ---------------------------------------------------------------------------
__global__ __launch_bounds__(512) void passB_kernel(
    const int* __restrict__ ei, const float* __restrict__ w,
    int* __restrict__ bcur_f, int* __restrict__ bcur_b,
    int2* __restrict__ binned_f, int2* __restrict__ binned_b, int E) {
  __shared__ int hf[MAXB], hb[MAXB], cf[MAXB], cb_[MAXB];
  int tid = threadIdx.x;
  for (int j = tid; j < MAXB; j += blockDim.x) { hf[j] = 0; hb[j] = 0; cf[j] = 0; cb_[j] = 0; }
  __syncthreads();
  size_t c0 = (size_t)blockIdx.x * E / gridDim.x;
  size_t c1 = (size_t)(blockIdx.x + 1) * E / gridDim.x;
  for (size_t e = c0 + tid; e < c1; e += blockDim.x) {
    int s = ntli(ei + e), d = ntli(ei + E + e);
    atomicAdd(&hf[d >> BSH], 1);
    atomicAdd(&hb[s >> BSH], 1);
  }
  __syncthreads();
  for (int j = tid; j < MAXB; j += blockDim.x) {
    int v = hf[j];
    if (v) hf[j] = atomicAdd(&bcur_f[j], v);
    int u = hb[j];
    if (u) hb[j] = atomicAdd(&bcur_b[j], u);
  }
  __syncthreads();
  for (size_t e = c0 + tid; e < c1; e += blockDim.x) {
    int s = ntli(ei + e), d = ntli(ei + E + e);
    int wb = __float_as_int(ntlf(w + e));
    int bf = d >> BSH;
    int pf = hf[bf] + atomicAdd(&cf[bf], 1);
    binned_f[pf] = make_int2(s | ((d & BMSK) << 17), wb);
    int bb = s >> BSH;
    int pb = hb[bb] + atomicAdd(&cb_[bb], 1);
    binned_b[pb] = make_int2(d | ((s & BMSK) << 17), wb);
  }
}

// ---------------------------------------------------------------------------
// Build 4: per-bucket CSR finalize (degrees over DECODED quantized weights).
// dir0 (fwd, keyed by dst) -> inv_in; dir1 (bwd, keyed by src) -> inv_out.
// ---------------------------------------------------------------------------
__global__ __launch_bounds__(256) void passC_kernel(
    const int2* __restrict__ binned_f, const int2* __restrict__ binned_b,
    const int* __restrict__ bbase_f, const int* __restrict__ bbase_b,
    int* __restrict__ adj_f, int* __restrict__ adj_b,
    int* __restrict__ rs_f, int* __restrict__ rs_b,
    float* __restrict__ inv_in, float* __restrict__ inv_out, int N) {
  int dir = blockIdx.y;
  const int2* binned = dir ? binned_b : binned_f;
  const int* bbase   = dir ? bbase_b  : bbase_f;
  int* adj           = dir ? adj_b    : adj_f;
  int* rs            = dir ? rs_b     : rs_f;
  float* inv         = dir ? inv_out  : inv_in;
  int b = blockIdx.x;
  int base = bbase[b], end = bbase[b + 1];
  __shared__ int cnt[256]; __shared__ float wsum[256];
  __shared__ int loc[256]; __shared__ int cur[256];
  int tid = threadIdx.x;
  cnt[tid] = 0; wsum[tid] = 0.f; cur[tid] = 0;
  __syncthreads();
  for (int i = base + tid; i < end; i += 256) {
    int2 it = binned[i];
    int nl = (it.x >> 17) & BMSK;
    atomicAdd(&cnt[nl], 1);
    atomicAdd(&wsum[nl], qdec(qenc(__int_as_float(it.y))));
  }
  __syncthreads();
  int v = cnt[tid];
  loc[tid] = v;
  __syncthreads();
  for (int off = 1; off < 256; off <<= 1) {
    int a = (tid >= off) ? loc[tid - off] : 0;
    __syncthreads();
    loc[tid] += a;
    __syncthreads();
  }
  int excl = loc[tid] - v;
  int node = (b << BSH) + tid;
  if (node < N) {
    rs[node] = base + excl;
    inv[node] = 1.f / fmaxf(wsum[tid], 1e-12f);
  }
  __syncthreads();
  loc[tid] = excl;
  __syncthreads();
  for (int i = base + tid; i < end; i += 256) {
    int2 it = binned[i];
    int nl = (it.x >> 17) & BMSK;
    int p = base + loc[nl] + atomicAdd(&cur[nl], 1);
    adj[p] = (it.x & 0x1FFFF) | (int)(qenc(__int_as_float(it.y)) << 17);
  }
}

// ---------------------------------------------------------------------------
// Output A: w_fwd = ew * inv_out[src]
// ---------------------------------------------------------------------------
__global__ __launch_bounds__(256) void wfout_kernel(
    const int* __restrict__ ei, const float* __restrict__ ew,
    const float* __restrict__ inv_out, float* __restrict__ wf, int E) {
  for (int e = blockIdx.x * blockDim.x + threadIdx.x; e < E;
       e += gridDim.x * blockDim.x)
    ntsf(wf + e, ntlf(ew + e) * inv_out[ntli(ei + e)]);
}

// ---------------------------------------------------------------------------
// Node phase A: block = 4 waves = 64 nodes; wave-uniform weight indexing
// (scalar s_load path). Emits fp16 PA (p1 gather input, pre-scaled) and
// fp16 accCx = x @ WpackC[0:35] (the r-independent part of the XHr
// projection, hoisted out of p2).
// ---------------------------------------------------------------------------
__global__ __launch_bounds__(256) void nodeA_kernel(
    const float* __restrict__ x,
    const float* __restrict__ W1, const float* __restrict__ b1,
    const float* __restrict__ W2, const float* __restrict__ b2,
    const float* __restrict__ bz, const float* __restrict__ br,
    const float* __restrict__ WpackA, const float* __restrict__ WpackC,
    const float* __restrict__ inv_out, const float* __restrict__ inv_in,
    float* __restrict__ h1, float* __restrict__ accDz,
    float* __restrict__ accDr, __half* __restrict__ PA_f,
    __half* __restrict__ PA_b, __half* __restrict__ accCx, int N) {
  __shared__ float part[4][64][5];
  int tid = threadIdx.x;
  int lane = tid & 63;
  int q = __builtin_amdgcn_readfirstlane(tid >> 6);
  int n = blockIdx.x * 64 + lane;
  bool act = n < N;
  float xv[40];
  const float* xr = x + (size_t)n * F_IN;
  #pragma unroll
  for (int i = 0; i < F_IN; i++) xv[i] = act ? ntlf(xr + i) : 0.f;

  float h5[5] = {0.f, 0.f, 0.f, 0.f, 0.f};
  int hbase = q * 25;
  for (int k = 0; k < 25; k++) {
    int hh = hbase + k;
    float a = b1[hh];
    #pragma unroll
    for (int i = 0; i < F_IN; i++) a = fmaf(xv[i], W1[i * HID + hh], a);
    a = fmaxf(a, 0.f);
    #pragma unroll
    for (int o = 0; o < 5; o++) h5[o] = fmaf(a, W2[hh * 5 + o], h5[o]);
  }
  #pragma unroll
  for (int o = 0; o < 5; o++) part[q][lane][o] = h5[o];
  __syncthreads();
  #pragma unroll
  for (int o = 0; o < 5; o++) {
    h5[o] = part[0][lane][o] + part[1][lane][o] + part[2][lane][o] +
            part[3][lane][o] + b2[o];
    xv[F_IN + o] = h5[o];
  }
  if (!act) return;
  if (q == 0) {
    #pragma unroll
    for (int o = 0; o < 5; o++) ntsf(h1 + (size_t)n * 5 + o, h5[o]);
  }
  float sOut = inv_out[n], sIn = inv_in[n];
  // 75 columns: 0-49 WpackA (XH), 50-74 WpackC[0:35] (x only)
  int c0 = q * 19, c1 = min(c0 + 19, 75);
  for (int c = c0; c < c1; c++) {
    float a = 0.f;
    if (c < 50) {
      #pragma unroll
      for (int i = 0; i < 40; i++) a = fmaf(xv[i], WpackA[i * 50 + c], a);
    } else {
      #pragma unroll
      for (int i = 0; i < F_IN; i++) a = fmaf(xv[i], WpackC[i * 25 + (c - 50)], a);
    }
    if (c < 5)       ntsf(accDz + (size_t)n * 5 + c, a + bz[c]);
    else if (c < 10) ntsf(accDr + (size_t)n * 5 + (c - 5), a + br[c - 5]);
    else if (c < 30) PA_f[(size_t)n * 20 + (c - 10)] = __float2half(a * sOut);
    else if (c < 50) PA_b[(size_t)n * 20 + (c - 30)] = __float2half(a * sIn);
    else             ntsh(accCx + (size_t)n * 25 + (c - 50), a);
  }
}

// ---------------------------------------------------------------------------
// P1: 1-hop fwd+bwd. DIR-PER-BLOCK (blockIdx&1): workgroups round-robin onto
// XCDs, so each XCD's L2 caches only ONE direction's 4MB PA array (fits).
// Within a dir: (node,half) pairs on adjacent lanes share adj reads.
// half0 -> Q1 fp32 (node-local); half1 -> Q2 fp16 (pre-scaled 2-hop input).
// ---------------------------------------------------------------------------
__global__ __launch_bounds__(256) void p1_kernel(
    const int* __restrict__ rs_f, const int* __restrict__ rs_b,
    const int* __restrict__ adj_f, const int* __restrict__ adj_b,
    const __half* __restrict__ PA_f, const __half* __restrict__ PA_b,
    const float* __restrict__ inv_out, const float* __restrict__ inv_in,
    float* __restrict__ Q1_f, float* __restrict__ Q1_b,
    __half* __restrict__ Q2_f, __half* __restrict__ Q2_b, int N) {
  int dir = blockIdx.x & 1;
  int idx = (blockIdx.x >> 1) * 256 + threadIdx.x;
  if (idx >= 2 * N) return;
  int n = idx >> 1, half = idx & 1;
  const int* rs  = dir ? rs_b : rs_f;
  const int* adj = dir ? adj_b : adj_f;
  const __half* PA = dir ? PA_b : PA_f;
  int i0 = rs[n], i1 = rs[n + 1];
  float acc[10];
  #pragma unroll
  for (int c = 0; c < 10; c++) acc[c] = 0.f;
  for (int i = i0; i < i1; i++) {
    int a = ntli(adj + i);
    float w = qdec(((unsigned)a) >> 17);
    const unsigned* row =
        (const unsigned*)(PA + (size_t)(a & 0x1FFFF) * 20) + half * 5;
    unsigned u0 = row[0], u1 = row[1], u2 = row[2], u3 = row[3], u4 = row[4];
    float2 f0 = uph2(u0), f1 = uph2(u1), f2 = uph2(u2), f3 = uph2(u3),
           f4 = uph2(u4);
    acc[0] = fmaf(w, f0.x, acc[0]); acc[1] = fmaf(w, f0.y, acc[1]);
    acc[2] = fmaf(w, f1.x, acc[2]); acc[3] = fmaf(w, f1.y, acc[3]);
    acc[4] = fmaf(w, f2.x, acc[4]); acc[5] = fmaf(w, f2.y, acc[5]);
    acc[6] = fmaf(w, f3.x, acc[6]); acc[7] = fmaf(w, f3.y, acc[7]);
    acc[8] = fmaf(w, f4.x, acc[8]); acc[9] = fmaf(w, f4.y, acc[9]);
  }
  if (!half) {
    float* q = (dir ? Q1_b : Q1_f) + (size_t)n * 10;
    #pragma unroll
    for (int c = 0; c < 10; c++) ntsf(q + c, acc[c]);
  } else {
    float sc = dir ? inv_in[n] : inv_out[n];
    unsigned* q = (unsigned*)((dir ? Q2_b : Q2_f) + (size_t)n * 10);
    q[0] = pkh2(acc[0] * sc, acc[1] * sc);
    q[1] = pkh2(acc[2] * sc, acc[3] * sc);
    q[2] = pkh2(acc[4] * sc, acc[5] * sc);
    q[3] = pkh2(acc[6] * sc, acc[7] * sc);
    q[4] = pkh2(acc[8] * sc, acc[9] * sc);
  }
}

// ---------------------------------------------------------------------------
// P2: 2-hop gather (fp16 Q2, lane0 fwd / lane1 bwd, shfl-sum) + nodeB body.
// X-projection precomputed (accCx); only the 5x25 h-part computed here.
// Writes Zg, accDh fp32; PH fp16 [N][12] (h0-4 Fh1, h6-10 Fh2; pre-scaled).
// ---------------------------------------------------------------------------
__global__ __launch_bounds__(256) void p2_kernel(
    const int* __restrict__ rs_f, const int* __restrict__ rs_b,
    const int* __restrict__ adj_f, const int* __restrict__ adj_b,
    const __half* __restrict__ Q2_f, const __half* __restrict__ Q2_b,
    const float* __restrict__ Q1_f, const float* __restrict__ Q1_b,
    const float* __restrict__ accDz, const float* __restrict__ accDr,
    const __half* __restrict__ accCx, const float* __restrict__ h1,
    const float* __restrict__ bh, const float* __restrict__ WpackC,
    const float* __restrict__ inv_out, const float* __restrict__ inv_in,
    float* __restrict__ Zg, float* __restrict__ accDh,
    __half* __restrict__ PH_f, __half* __restrict__ PH_b, int N) {
  int t = blockIdx.x * blockDim.x + threadIdx.x;
  int n = t >> 1, l = t & 1;
  if (n >= N) return;
  const int* rs  = l ? rs_b : rs_f;
  const int* adj = l ? adj_b : adj_f;
  const __half* Q2 = l ? Q2_b : Q2_f;
  float a[10];
  #pragma unroll
  for (int c = 0; c < 10; c++) a[c] = 0.f;
  int i0 = rs[n], i1 = rs[n + 1];
  for (int i = i0; i < i1; i++) {
    int e = ntli(adj + i);
    float w = qdec(((unsigned)e) >> 17);
    const unsigned* row = (const unsigned*)(Q2 + (size_t)(e & 0x1FFFF) * 10);
    unsigned u0 = row[0], u1 = row[1], u2 = row[2], u3 = row[3], u4 = row[4];
    float2 f0 = uph2(u0), f1 = uph2(u1), f2 = uph2(u2), f3 = uph2(u3),
           f4 = uph2(u4);
    a[0] = fmaf(w, f0.x, a[0]); a[1] = fmaf(w, f0.y, a[1]);
    a[2] = fmaf(w, f1.x, a[2]); a[3] = fmaf(w, f1.y, a[3]);
    a[4] = fmaf(w, f2.x, a[4]); a[5] = fmaf(w, f2.y, a[5]);
    a[6] = fmaf(w, f3.x, a[6]); a[7] = fmaf(w, f3.y, a[7]);
    a[8] = fmaf(w, f4.x, a[8]); a[9] = fmaf(w, f4.y, a[9]);
  }
  #pragma unroll
  for (int c = 0; c < 10; c++) a[c] += __shfl_xor(a[c], 1);  // aF+aB in both

  float r[5], zv[5];
  #pragma unroll
  for (int o = 0; o < 5; o++) {
    float zp = accDz[(size_t)n * 5 + o] + ntlf(Q1_f + (size_t)n * 10 + o) +
               ntlf(Q1_b + (size_t)n * 10 + o) + 2.f * a[o];
    float rp = accDr[(size_t)n * 5 + o] + ntlf(Q1_f + (size_t)n * 10 + 5 + o) +
               ntlf(Q1_b + (size_t)n * 10 + 5 + o) + 2.f * a[5 + o];
    zv[o] = 1.f / (1.f + __expf(-zp));
    r[o]  = 1.f / (1.f + __expf(-rp));
  }
  if (l == 0) {
    #pragma unroll
    for (int o = 0; o < 5; o++) ntsf(Zg + (size_t)n * 5 + o, zv[o]);
  }
  float hr[5];
  #pragma unroll
  for (int o = 0; o < 5; o++) hr[o] = ntlf(h1 + (size_t)n * 5 + o) * r[o];

  float sOut = inv_out[n], sIn = inv_in[n];
  int c0 = l ? 13 : 0, c1 = l ? 25 : 13;
  for (int c = c0; c < c1; c++) {
    float acc = ntlh(accCx + (size_t)n * 25 + c);
    #pragma unroll
    for (int o = 0; o < 5; o++) acc = fmaf(hr[o], WpackC[(F_IN + o) * 25 + c], acc);
    if (c < 5)       ntsf(accDh + (size_t)n * 5 + c, acc + bh[c]);
    else if (c < 10) PH_f[(size_t)n * 12 + (c - 5)] = __float2half(acc * sOut);
    else if (c < 15) PH_f[(size_t)n * 12 + 6 + (c - 10)] = __float2half(acc * sOut);
    else if (c < 20) PH_b[(size_t)n * 12 + (c - 15)] = __float2half(acc * sIn);
    else             PH_b[(size_t)n * 12 + 6 + (c - 20)] = __float2half(acc * sIn);
  }
}

// ---------------------------------------------------------------------------
// P3: 1-hop h, DIR-PER-BLOCK (as P1); paired-lane split over PH's two 5-col
// groups (h0-4 Fh1 -> Q1h fp32; h6-10 Fh2 -> Q2h fp16, pre-scaled).
// ---------------------------------------------------------------------------
__global__ __launch_bounds__(256) void p3_kernel(
    const int* __restrict__ rs_f, const int* __restrict__ rs_b,
    const int* __restrict__ adj_f, const int* __restrict__ adj_b,
    const __half* __restrict__ PH_f, const __half* __restrict__ PH_b,
    const float* __restrict__ inv_out, const float* __restrict__ inv_in,
    float* __restrict__ Q1h_f, float* __restrict__ Q1h_b,
    __half* __restrict__ Q2h_f, __half* __restrict__ Q2h_b, int N) {
  int dir = blockIdx.x & 1;
  int idx = (blockIdx.x >> 1) * 256 + threadIdx.x;
  if (idx >= 2 * N) return;
  int n = idx >> 1, half = idx & 1;
  const int* rs  = dir ? rs_b : rs_f;
  const int* adj = dir ? adj_b : adj_f;
  const __half* PH = dir ? PH_b : PH_f;
  int i0 = rs[n], i1 = rs[n + 1];
  float acc[5];
  #pragma unroll
  for (int c = 0; c < 5; c++) acc[c] = 0.f;
  for (int i = i0; i < i1; i++) {
    int a = ntli(adj + i);
    float w = qdec(((unsigned)a) >> 17);
    const unsigned* row =
        (const unsigned*)(PH + (size_t)(a & 0x1FFFF) * 12) + half * 3;
    unsigned u0 = row[0], u1 = row[1], u2 = row[2];
    float2 f0 = uph2(u0), f1 = uph2(u1), f2 = uph2(u2);
    acc[0] = fmaf(w, f0.x, acc[0]); acc[1] = fmaf(w, f0.y, acc[1]);
    acc[2] = fmaf(w, f1.x, acc[2]); acc[3] = fmaf(w, f1.y, acc[3]);
    acc[4] = fmaf(w, f2.x, acc[4]);
  }
  if (!half) {
    float* q = (dir ? Q1h_b : Q1h_f) + (size_t)n * 5;
    #pragma unroll
    for (int c = 0; c < 5; c++) ntsf(q + c, acc[c]);
  } else {
    float sc = dir ? inv_in[n] : inv_out[n];
    unsigned* q = (unsigned*)((dir ? Q2h_b : Q2h_f) + (size_t)n * 8);
    q[0] = pkh2(acc[0] * sc, acc[1] * sc);
    q[1] = pkh2(acc[2] * sc, acc[3] * sc);
    q[2] = pkh2(acc[4] * sc, 0.f);
  }
}

// ---------------------------------------------------------------------------
// P4: 2-hop h gather (fp16 Q2h, lane-split) + nodeC body -> y. 2N threads.
// ---------------------------------------------------------------------------
__global__ __launch_bounds__(256) void p4_kernel(
    const int* __restrict__ rs_f, const int* __restrict__ rs_b,
    const int* __restrict__ adj_f, const int* __restrict__ adj_b,
    const __half* __restrict__ Q2h_f, const __half* __restrict__ Q2h_b,
    const float* __restrict__ Q1h_f, const float* __restrict__ Q1h_b,
    const float* __restrict__ accDh, const float* __restrict__ Zg,
    const float* __restrict__ h1, const float* __restrict__ Wl,
    const float* __restrict__ bl, float* __restrict__ y, int N) {
  int t = blockIdx.x * blockDim.x + threadIdx.x;
  int n = t >> 1, l = t & 1;
  if (n >= N) return;
  const int* rs  = l ? rs_b : rs_f;
  const int* adj = l ? adj_b : adj_f;
  const __half* Q2h = l ? Q2h_b : Q2h_f;
  float a[5];
  #pragma unroll
  for (int c = 0; c < 5; c++) a[c] = 0.f;
  int i0 = rs[n], i1 = rs[n + 1];
  for (int i = i0; i < i1; i++) {
    int e = ntli(adj + i);
    float w = qdec(((unsigned)e) >> 17);
    const unsigned* row = (const unsigned*)(Q2h + (size_t)(e & 0x1FFFF) * 8);
    unsigned u0 = row[0], u1 = row[1], u2 = row[2];
    float2 f0 = uph2(u0), f1 = uph2(u1), f2 = uph2(u2);
    a[0] = fmaf(w, f0.x, a[0]); a[1] = fmaf(w, f0.y, a[1]);
    a[2] = fmaf(w, f1.x, a[2]); a[3] = fmaf(w, f1.y, a[3]);
    a[4] = fmaf(w, f2.x, a[4]);
  }
  #pragma unroll
  for (int c = 0; c < 5; c++) a[c] += __shfl_xor(a[c], 1);
  if (l) return;
  float acc = bl[0];
  #pragma unroll
  for (int o = 0; o < 5; o++) {
    float pre = ntlf(accDh + (size_t)n * 5 + o) + ntlf(Q1h_f + (size_t)n * 5 + o) +
                ntlf(Q1h_b + (size_t)n * 5 + o) + 2.f * a[o];
    float ht = tanhf(pre);
    float z = ntlf(Zg + (size_t)n * 5 + o);
    float H = z * ntlf(h1 + (size_t)n * 5 + o) + (1.f - z) * ht;
    acc += fmaxf(H, 0.f) * Wl[o];
  }
  ntsf(y + n, acc);
}

// ---------------------------------------------------------------------------
extern "C" void kernel_launch(void* const* d_in, const int* in_sizes, int n_in,
                              void* d_out, int out_size, void* d_ws, size_t ws_size,
                              hipStream_t stream) {
  const float* x  = (const float*)d_in[0];
  const int*   ei = (const int*)d_in[1];
  const float* ew = (const float*)d_in[2];
  const float* W1 = (const float*)d_in[3];
  const float* b1 = (const float*)d_in[4];
  const float* W2 = (const float*)d_in[5];
  const float* b2 = (const float*)d_in[6];
  const float* Wz = (const float*)d_in[7];
  const float* bz = (const float*)d_in[8];
  const float* Wr = (const float*)d_in[9];
  const float* br = (const float*)d_in[10];
  const float* Wh = (const float*)d_in[11];
  const float* bh = (const float*)d_in[12];
  const float* Wl = (const float*)d_in[13];
  const float* bl = (const float*)d_in[14];

  const int N = in_sizes[0] / F_IN;
  const int E = in_sizes[2];
  const int nbuck = ((N - 1) >> BSH) + 1;   // N <= 131072 assumed

  float* out = (float*)d_out;
  float* y_out  = out;          // [N]
  float* wf_out = out + N;      // [E]  == output A

  // Workspace layout (4-byte words; 8B alignment maintained for packed loads)
  float* W = (float*)d_ws;
  size_t o = 0;
  int* bcnt_f  = (int*)(W + o); o += MAXB;       // zeroed as one block
  int* bcnt_b  = (int*)(W + o); o += MAXB;
  int* bbase_f = (int*)(W + o); o += MAXB + 2;
  int* bbase_b = (int*)(W + o); o += MAXB + 2;
  int* bcur_f  = (int*)(W + o); o += MAXB;
  int* bcur_b  = (int*)(W + o); o += MAXB;
  int* rs_f    = (int*)(W + o); o += (size_t)N + 1;
  int* rs_b    = (int*)(W + o); o += (size_t)N + 1;
  float* inv_out = W + o; o += N;
  float* inv_in  = W + o; o += N;
  int* adj_f   = (int*)(W + o); o += (size_t)E;
  int* adj_b   = (int*)(W + o); o += (size_t)E;
  float* h1    = W + o; o += (size_t)5 * N;
  float* accDz = W + o; o += (size_t)5 * N;
  float* accDr = W + o; o += (size_t)5 * N;
  float* accDh = W + o; o += (size_t)5 * N;
  float* Zg    = W + o; o += (size_t)5 * N;
  __half* accCx = (__half*)(W + o); o += (size_t)13 * N;  // [N][25] fp16
  o = (o + 1) & ~(size_t)1;                 // 8B align
  size_t prop0 = o;                         // binned aliases from here
  __half* PA_f = (__half*)(W + o); o += (size_t)10 * N;   // [N][20] fp16
  __half* PA_b = (__half*)(W + o); o += (size_t)10 * N;
  float* Q1_f  = W + o; o += (size_t)10 * N;              // [N][10] fp32
  float* Q1_b  = W + o; o += (size_t)10 * N;
  __half* Q2_f = (__half*)(W + o); o += (size_t)5 * N;    // [N][10] fp16
  __half* Q2_b = (__half*)(W + o); o += (size_t)5 * N;
  __half* PH_f = (__half*)(W + o); o += (size_t)6 * N;    // [N][12] fp16
  __half* PH_b = (__half*)(W + o); o += (size_t)6 * N;
  float* Q1h_f = W + o; o += (size_t)5 * N;               // [N][5] fp32
  float* Q1h_b = W + o; o += (size_t)5 * N;
  o = (o + 1) & ~(size_t)1;
  __half* Q2h_f = (__half*)(W + o); o += (size_t)4 * N;   // [N][8] fp16
  __half* Q2h_b = (__half*)(W + o); o += (size_t)4 * N;
  float* WpackA = W + o; o += 2000;
  float* WpackC = W + o; o += 1000;

  // binned scratch aliases the prop region (consumed by passC before nodeA
  // writes anything there); needs 4E words <= 80N words.
  int2* binned_f = (int2*)(W + prop0);
  int2* binned_b = binned_f + E;

  const int NB2 = (2 * N + 255) / 256;
  const int NBd = 2 * ((2 * N + 255) / 256);   // dir-per-block grids
  const int NBn = (N + 63) / 64;

  // 1. packed weights
  prep_weights<<<8, 256, 0, stream>>>(Wz, Wr, Wh, WpackA, WpackC);

  // 2. CSR build
  hipMemsetAsync(bcnt_f, 0, 2 * MAXB * sizeof(int), stream);
  hist_kernel<<<512, 256, 0, stream>>>(ei, bcnt_f, bcnt_b, E);
  scanb_kernel<<<1, MAXB, 0, stream>>>(bcnt_f, bcnt_b, bbase_f, bbase_b,
                                       bcur_f, bcur_b, rs_f, rs_b,
                                       nbuck, N, E);
  passB_kernel<<<256, 512, 0, stream>>>(ei, ew, bcur_f, bcur_b,
                                        binned_f, binned_b, E);
  passC_kernel<<<dim3(nbuck, 2), 256, 0, stream>>>(
      binned_f, binned_b, bbase_f, bbase_b, adj_f, adj_b,
      rs_f, rs_b, inv_in, inv_out, N);
  wfout_kernel<<<1024, 256, 0, stream>>>(ei, ew, inv_out, wf_out, E);

  // 3. node phase A
  nodeA_kernel<<<NBn, 256, 0, stream>>>(x, W1, b1, W2, b2, bz, br, WpackA,
                                        WpackC, inv_out, inv_in,
                                        h1, accDz, accDr, PA_f, PA_b,
                                        accCx, N);

  // 4. fused propagation + gate phases
  p1_kernel<<<NBd, 256, 0, stream>>>(rs_f, rs_b, adj_f, adj_b, PA_f, PA_b,
                                     inv_out, inv_in, Q1_f, Q1_b, Q2_f, Q2_b, N);
  p2_kernel<<<NB2, 256, 0, stream>>>(rs_f, rs_b, adj_f, adj_b, Q2_f, Q2_b,
                                     Q1_f, Q1_b, accDz, accDr, accCx, h1, bh,
                                     WpackC, inv_out, inv_in,
                                     Zg, accDh, PH_f, PH_b, N);
  p3_kernel<<<NBd, 256, 0, stream>>>(rs_f, rs_b, adj_f, adj_b, PH_f, PH_b,
                                     inv_out, inv_in, Q1h_f, Q1h_b,
                                     Q2h_f, Q2h_b, N);
  p4_kernel<<<NB2, 256, 0, stream>>>(rs_f, rs_b, adj_f, adj_b, Q2h_f, Q2h_b,
                                     Q1h_f, Q1h_b, accDh, Zg, h1, Wl, bl,
                                     y_out, N);
}

// Round 8
// 467.166 us; speedup vs baseline: 1.1418x; 1.1418x over previous
//
#include <hip/hip_runtime.h>
#include <hip/hip_fp16.h>

#define F_IN 35
#define F_OUT 5
#define HID 100
#define BSH 8              // 256 node-ids per bucket
#define BMSK 255
#define MAXB 512           // max buckets (requires N <= 131072)

// 15-bit relative float for w in (0,1]: 4-bit exp, 11-bit mantissa.
__device__ __forceinline__ unsigned qenc(float w) {
  unsigned b = __float_as_uint(w);
  int e = 127 - (int)((b >> 23) & 0xFF);
  unsigned m = (b >> 12) & 0x7FFu;
  if (e < 0) { e = 0; m = 0; }
  if (e > 15) { e = 15; m = 0; }
  return ((unsigned)e << 11) | m;
}
__device__ __forceinline__ float qdec(unsigned q) {
  return __uint_as_float(((127u - (q >> 11)) << 23) | ((q & 0x7FFu) << 12));
}

__device__ __forceinline__ float2 uph2(unsigned u) {
  __half2 h = *reinterpret_cast<const __half2*>(&u);
  return __half22float2(h);
}
__device__ __forceinline__ unsigned pkh2(float a, float b) {
  __half2 h = __floats2half2_rn(a, b);
  return *reinterpret_cast<const unsigned*>(&h);
}

// Non-temporal LOADS only, for pure streaming data (edge lists, adjacency).
// NT STORES are forbidden here: round-7 showed nt on strided scalar stores
// causes ~6x HBM write amplification (110MB vs 20MB in nodeA) and evicts
// producer->consumer L2 lines.
__device__ __forceinline__ int ntli(const int* p) {
  return __builtin_nontemporal_load(p);
}
__device__ __forceinline__ float ntlf(const float* p) {
  return __builtin_nontemporal_load(p);
}
__device__ __forceinline__ void ntsf(float* p, float v) {
  __builtin_nontemporal_store(v, p);   // used ONLY for coalesced final output
}

// ---------------------------------------------------------------------------
// Weight prep.
// WpackA [40x50]: 0-4 Dz, 5-9 Dr, 10-14 Fz1, 15-19 Fr1, 20-24 Fz2, 25-29 Fr2,
//                 30-34 Bz1, 35-39 Br1, 40-44 Bz2, 45-49 Br2
// WpackC [40x25]: 0-4 Dh, 5-9 Fh1, 10-14 Fh2, 15-19 Bh1, 20-24 Bh2
// ---------------------------------------------------------------------------
__global__ __launch_bounds__(256) void prep_weights(
    const float* __restrict__ Wz, const float* __restrict__ Wr,
    const float* __restrict__ Wh,
    float* __restrict__ WpackA, float* __restrict__ WpackC) {
  int t = blockIdx.x * blockDim.x + threadIdx.x;
  if (t < 40 * 50) {
    int i = t / 50, c = t % 50;
    auto W = [&](const float* Wp, int d, int k, int o) {
      return Wp[((d * 3 + k) * 40 + i) * 5 + o];
    };
    float v;
    if (c < 5)       v = W(Wz,0,0,c)    + W(Wz,1,0,c)    - W(Wz,0,2,c)    - W(Wz,1,2,c);
    else if (c < 10) v = W(Wr,0,0,c-5)  + W(Wr,1,0,c-5)  - W(Wr,0,2,c-5)  - W(Wr,1,2,c-5);
    else if (c < 15) v = W(Wz,0,1,c-10);
    else if (c < 20) v = W(Wr,0,1,c-15);
    else if (c < 25) v = W(Wz,0,2,c-20);
    else if (c < 30) v = W(Wr,0,2,c-25);
    else if (c < 35) v = W(Wz,1,1,c-30);
    else if (c < 40) v = W(Wr,1,1,c-35);
    else if (c < 45) v = W(Wz,1,2,c-40);
    else             v = W(Wr,1,2,c-45);
    WpackA[i * 50 + c] = v;
  }
  if (t < 40 * 25) {
    int i = t / 25, c = t % 25;
    auto W = [&](const float* Wp, int d, int k, int o) {
      return Wp[((d * 3 + k) * 40 + i) * 5 + o];
    };
    float v;
    if (c < 5)       v = W(Wh,0,0,c)    + W(Wh,1,0,c)    - W(Wh,0,2,c)    - W(Wh,1,2,c);
    else if (c < 10) v = W(Wh,0,1,c-5);
    else if (c < 15) v = W(Wh,0,2,c-10);
    else if (c < 20) v = W(Wh,1,1,c-15);
    else             v = W(Wh,1,2,c-20);
    WpackC[i * 25 + c] = v;
  }
}

// ---------------------------------------------------------------------------
// Build 1: bucket histograms (LDS pre-aggregated).
// ---------------------------------------------------------------------------
__global__ __launch_bounds__(256) void hist_kernel(
    const int* __restrict__ ei, int* __restrict__ bcnt_f,
    int* __restrict__ bcnt_b, int E) {
  __shared__ int h[2 * MAXB];
  for (int j = threadIdx.x; j < 2 * MAXB; j += blockDim.x) h[j] = 0;
  __syncthreads();
  for (int e = blockIdx.x * blockDim.x + threadIdx.x; e < E;
       e += gridDim.x * blockDim.x) {
    int s = ntli(ei + e), d = ntli(ei + E + e);
    atomicAdd(&h[d >> BSH], 1);
    atomicAdd(&h[MAXB + (s >> BSH)], 1);
  }
  __syncthreads();
  for (int j = threadIdx.x; j < 2 * MAXB; j += blockDim.x) {
    int v = h[j];
    if (v) {
      if (j < MAXB) atomicAdd(&bcnt_f[j], v);
      else          atomicAdd(&bcnt_b[j - MAXB], v);
    }
  }
}

// ---------------------------------------------------------------------------
// Build 2: bucket exclusive scan -> bases + cursors; rs[N]=E sentinels.
// ---------------------------------------------------------------------------
__global__ __launch_bounds__(512) void scanb_kernel(
    const int* __restrict__ bcnt_f, const int* __restrict__ bcnt_b,
    int* __restrict__ bbase_f, int* __restrict__ bbase_b,
    int* __restrict__ bcur_f, int* __restrict__ bcur_b,
    int* __restrict__ rs_f, int* __restrict__ rs_b,
    int nbuck, int N, int E) {
  __shared__ int s0[MAXB], s1[MAXB];
  int t = threadIdx.x;
  s0[t] = (t < nbuck) ? bcnt_f[t] : 0;
  s1[t] = (t < nbuck) ? bcnt_b[t] : 0;
  __syncthreads();
  for (int off = 1; off < MAXB; off <<= 1) {
    int a = (t >= off) ? s0[t - off] : 0;
    int b = (t >= off) ? s1[t - off] : 0;
    __syncthreads();
    s0[t] += a; s1[t] += b;
    __syncthreads();
  }
  bbase_f[t + 1] = s0[t];
  bbase_b[t + 1] = s1[t];
  bcur_f[t] = t ? s0[t - 1] : 0;
  bcur_b[t] = t ? s1[t - 1] : 0;
  if (t == 0) { bbase_f[0] = 0; bbase_b[0] = 0; rs_f[N] = E; rs_b[N] = E; }
}

// ---------------------------------------------------------------------------
// Build 3: bin edges into compact bucket regions. Item: other|keylow<<17, w.
// ---------------------------------------------------------------------------
__global__ __launch_bounds__(512) void passB_kernel(
    const int* __restrict__ ei, const float* __restrict__ w,
    int* __restrict__ bcur_f, int* __restrict__ bcur_b,
    int2* __restrict__ binned_f, int2* __restrict__ binned_b, int E) {
  __shared__ int hf[MAXB], hb[MAXB], cf[MAXB], cb_[MAXB];
  int tid = threadIdx.x;
  for (int j = tid; j < MAXB; j += blockDim.x) { hf[j] = 0; hb[j] = 0; cf[j] = 0; cb_[j] = 0; }
  __syncthreads();
  size_t c0 = (size_t)blockIdx.x * E / gridDim.x;
  size_t c1 = (size_t)(blockIdx.x + 1) * E / gridDim.x;
  for (size_t e = c0 + tid; e < c1; e += blockDim.x) {
    int s = ntli(ei + e), d = ntli(ei + E + e);
    atomicAdd(&hf[d >> BSH], 1);
    atomicAdd(&hb[s >> BSH], 1);
  }
  __syncthreads();
  for (int j = tid; j < MAXB; j += blockDim.x) {
    int v = hf[j];
    if (v) hf[j] = atomicAdd(&bcur_f[j], v);
    int u = hb[j];
    if (u) hb[j] = atomicAdd(&bcur_b[j], u);
  }
  __syncthreads();
  for (size_t e = c0 + tid; e < c1; e += blockDim.x) {
    int s = ntli(ei + e), d = ntli(ei + E + e);
    int wb = __float_as_int(ntlf(w + e));
    int bf = d >> BSH;
    int pf = hf[bf] + atomicAdd(&cf[bf], 1);
    binned_f[pf] = make_int2(s | ((d & BMSK) << 17), wb);
    int bb = s >> BSH;
    int pb = hb[bb] + atomicAdd(&cb_[bb], 1);
    binned_b[pb] = make_int2(d | ((s & BMSK) << 17), wb);
  }
}

// ---------------------------------------------------------------------------
// Build 4: per-bucket CSR finalize (degrees over DECODED quantized weights).
// dir0 (fwd, keyed by dst) -> inv_in; dir1 (bwd, keyed by src) -> inv_out.
// ---------------------------------------------------------------------------
__global__ __launch_bounds__(256) void passC_kernel(
    const int2* __restrict__ binned_f, const int2* __restrict__ binned_b,
    const int* __restrict__ bbase_f, const int* __restrict__ bbase_b,
    int* __restrict__ adj_f, int* __restrict__ adj_b,
    int* __restrict__ rs_f, int* __restrict__ rs_b,
    float* __restrict__ inv_in, float* __restrict__ inv_out, int N) {
  int dir = blockIdx.y;
  const int2* binned = dir ? binned_b : binned_f;
  const int* bbase   = dir ? bbase_b  : bbase_f;
  int* adj           = dir ? adj_b    : adj_f;
  int* rs            = dir ? rs_b     : rs_f;
  float* inv         = dir ? inv_out  : inv_in;
  int b = blockIdx.x;
  int base = bbase[b], end = bbase[b + 1];
  __shared__ int cnt[256]; __shared__ float wsum[256];
  __shared__ int loc[256]; __shared__ int cur[256];
  int tid = threadIdx.x;
  cnt[tid] = 0; wsum[tid] = 0.f; cur[tid] = 0;
  __syncthreads();
  for (int i = base + tid; i < end; i += 256) {
    int2 it = binned[i];
    int nl = (it.x >> 17) & BMSK;
    atomicAdd(&cnt[nl], 1);
    atomicAdd(&wsum[nl], qdec(qenc(__int_as_float(it.y))));
  }
  __syncthreads();
  int v = cnt[tid];
  loc[tid] = v;
  __syncthreads();
  for (int off = 1; off < 256; off <<= 1) {
    int a = (tid >= off) ? loc[tid - off] : 0;
    __syncthreads();
    loc[tid] += a;
    __syncthreads();
  }
  int excl = loc[tid] - v;
  int node = (b << BSH) + tid;
  if (node < N) {
    rs[node] = base + excl;
    inv[node] = 1.f / fmaxf(wsum[tid], 1e-12f);
  }
  __syncthreads();
  loc[tid] = excl;
  __syncthreads();
  for (int i = base + tid; i < end; i += 256) {
    int2 it = binned[i];
    int nl = (it.x >> 17) & BMSK;
    int p = base + loc[nl] + atomicAdd(&cur[nl], 1);
    adj[p] = (it.x & 0x1FFFF) | (int)(qenc(__int_as_float(it.y)) << 17);
  }
}

// ---------------------------------------------------------------------------
// Output A: w_fwd = ew * inv_out[src]  (nt store OK: coalesced final output)
// ---------------------------------------------------------------------------
__global__ __launch_bounds__(256) void wfout_kernel(
    const int* __restrict__ ei, const float* __restrict__ ew,
    const float* __restrict__ inv_out, float* __restrict__ wf, int E) {
  for (int e = blockIdx.x * blockDim.x + threadIdx.x; e < E;
       e += gridDim.x * blockDim.x)
    ntsf(wf + e, ntlf(ew + e) * inv_out[ntli(ei + e)]);
}

// ---------------------------------------------------------------------------
// Node phase A: block = 4 waves = 64 nodes; wave-uniform weight indexing
// (scalar s_load path). Emits fp16 PA (p1 gather input, pre-scaled) and
// fp16 accCx = x @ WpackC[0:35] (r-independent XHr part, hoisted from p2).
// All stores NORMAL (L2-merged).
// ---------------------------------------------------------------------------
__global__ __launch_bounds__(256) void nodeA_kernel(
    const float* __restrict__ x,
    const float* __restrict__ W1, const float* __restrict__ b1,
    const float* __restrict__ W2, const float* __restrict__ b2,
    const float* __restrict__ bz, const float* __restrict__ br,
    const float* __restrict__ WpackA, const float* __restrict__ WpackC,
    const float* __restrict__ inv_out, const float* __restrict__ inv_in,
    float* __restrict__ h1, float* __restrict__ accDz,
    float* __restrict__ accDr, __half* __restrict__ PA_f,
    __half* __restrict__ PA_b, __half* __restrict__ accCx, int N) {
  __shared__ float part[4][64][5];
  int tid = threadIdx.x;
  int lane = tid & 63;
  int q = __builtin_amdgcn_readfirstlane(tid >> 6);
  int n = blockIdx.x * 64 + lane;
  bool act = n < N;
  float xv[40];
  const float* xr = x + (size_t)n * F_IN;
  #pragma unroll
  for (int i = 0; i < F_IN; i++) xv[i] = act ? xr[i] : 0.f;

  float h5[5] = {0.f, 0.f, 0.f, 0.f, 0.f};
  int hbase = q * 25;
  for (int k = 0; k < 25; k++) {
    int hh = hbase + k;
    float a = b1[hh];
    #pragma unroll
    for (int i = 0; i < F_IN; i++) a = fmaf(xv[i], W1[i * HID + hh], a);
    a = fmaxf(a, 0.f);
    #pragma unroll
    for (int o = 0; o < 5; o++) h5[o] = fmaf(a, W2[hh * 5 + o], h5[o]);
  }
  #pragma unroll
  for (int o = 0; o < 5; o++) part[q][lane][o] = h5[o];
  __syncthreads();
  #pragma unroll
  for (int o = 0; o < 5; o++) {
    h5[o] = part[0][lane][o] + part[1][lane][o] + part[2][lane][o] +
            part[3][lane][o] + b2[o];
    xv[F_IN + o] = h5[o];
  }
  if (!act) return;
  if (q == 0) {
    #pragma unroll
    for (int o = 0; o < 5; o++) h1[(size_t)n * 5 + o] = h5[o];
  }
  float sOut = inv_out[n], sIn = inv_in[n];
  // 75 columns: 0-49 WpackA (XH), 50-74 WpackC[0:35] (x only)
  int c0 = q * 19, c1 = min(c0 + 19, 75);
  for (int c = c0; c < c1; c++) {
    float a = 0.f;
    if (c < 50) {
      #pragma unroll
      for (int i = 0; i < 40; i++) a = fmaf(xv[i], WpackA[i * 50 + c], a);
    } else {
      #pragma unroll
      for (int i = 0; i < F_IN; i++) a = fmaf(xv[i], WpackC[i * 25 + (c - 50)], a);
    }
    if (c < 5)       accDz[(size_t)n * 5 + c] = a + bz[c];
    else if (c < 10) accDr[(size_t)n * 5 + (c - 5)] = a + br[c - 5];
    else if (c < 30) PA_f[(size_t)n * 20 + (c - 10)] = __float2half(a * sOut);
    else if (c < 50) PA_b[(size_t)n * 20 + (c - 30)] = __float2half(a * sIn);
    else             accCx[(size_t)n * 25 + (c - 50)] = __float2half(a);
  }
}

// ---------------------------------------------------------------------------
// P1: 1-hop fwd+bwd. DIR-PER-BLOCK (blockIdx&1): each XCD's L2 caches mostly
// one direction's 4MB PA array. Paired lanes share (node,dir), 10-col halves.
// half0 -> Q1 fp32 (node-local); half1 -> Q2 fp16 [N][12] (two 5+pad groups:
// slots 0-4 = z 2-hop input, slots 6-10 = r 2-hop input; pre-scaled).
// ---------------------------------------------------------------------------
__global__ __launch_bounds__(256) void p1_kernel(
    const int* __restrict__ rs_f, const int* __restrict__ rs_b,
    const int* __restrict__ adj_f, const int* __restrict__ adj_b,
    const __half* __restrict__ PA_f, const __half* __restrict__ PA_b,
    const float* __restrict__ inv_out, const float* __restrict__ inv_in,
    float* __restrict__ Q1_f, float* __restrict__ Q1_b,
    __half* __restrict__ Q2_f, __half* __restrict__ Q2_b, int N) {
  int dir = blockIdx.x & 1;
  int idx = (blockIdx.x >> 1) * 256 + threadIdx.x;
  if (idx >= 2 * N) return;
  int n = idx >> 1, half = idx & 1;
  const int* rs  = dir ? rs_b : rs_f;
  const int* adj = dir ? adj_b : adj_f;
  const __half* PA = dir ? PA_b : PA_f;
  int i0 = rs[n], i1 = rs[n + 1];
  float acc[10];
  #pragma unroll
  for (int c = 0; c < 10; c++) acc[c] = 0.f;
  for (int i = i0; i < i1; i++) {
    int a = ntli(adj + i);
    float w = qdec(((unsigned)a) >> 17);
    const unsigned* row =
        (const unsigned*)(PA + (size_t)(a & 0x1FFFF) * 20) + half * 5;
    unsigned u0 = row[0], u1 = row[1], u2 = row[2], u3 = row[3], u4 = row[4];
    float2 f0 = uph2(u0), f1 = uph2(u1), f2 = uph2(u2), f3 = uph2(u3),
           f4 = uph2(u4);
    acc[0] = fmaf(w, f0.x, acc[0]); acc[1] = fmaf(w, f0.y, acc[1]);
    acc[2] = fmaf(w, f1.x, acc[2]); acc[3] = fmaf(w, f1.y, acc[3]);
    acc[4] = fmaf(w, f2.x, acc[4]); acc[5] = fmaf(w, f2.y, acc[5]);
    acc[6] = fmaf(w, f3.x, acc[6]); acc[7] = fmaf(w, f3.y, acc[7]);
    acc[8] = fmaf(w, f4.x, acc[8]); acc[9] = fmaf(w, f4.y, acc[9]);
  }
  if (!half) {
    float* q = (dir ? Q1_b : Q1_f) + (size_t)n * 10;
    #pragma unroll
    for (int c = 0; c < 10; c++) q[c] = acc[c];
  } else {
    float sc = dir ? inv_in[n] : inv_out[n];
    unsigned* q = (unsigned*)((dir ? Q2_b : Q2_f) + (size_t)n * 12);
    q[0] = pkh2(acc[0] * sc, acc[1] * sc);
    q[1] = pkh2(acc[2] * sc, acc[3] * sc);
    q[2] = pkh2(acc[4] * sc, 0.f);
    q[3] = pkh2(acc[5] * sc, acc[6] * sc);
    q[4] = pkh2(acc[7] * sc, acc[8] * sc);
    q[5] = pkh2(acc[9] * sc, 0.f);
  }
}

// ---------------------------------------------------------------------------
// P2: 2-hop gather + nodeB body, 4N threads. Quad lanes per node:
// sub = (dir<<1)|group; each gathers one (direction, 5-channel group) from
// Q2 [N][12]. Combine: shfl_xor(2) sums directions; shfl_xor(1) exchanges
// channel groups -> every lane holds full z/r 2-hop sums. Epilogue columns
// split 7/6/6/6 across the quad.
// ---------------------------------------------------------------------------
__global__ __launch_bounds__(256) void p2_kernel(
    const int* __restrict__ rs_f, const int* __restrict__ rs_b,
    const int* __restrict__ adj_f, const int* __restrict__ adj_b,
    const __half* __restrict__ Q2_f, const __half* __restrict__ Q2_b,
    const float* __restrict__ Q1_f, const float* __restrict__ Q1_b,
    const float* __restrict__ accDz, const float* __restrict__ accDr,
    const __half* __restrict__ accCx, const float* __restrict__ h1,
    const float* __restrict__ bh, const float* __restrict__ WpackC,
    const float* __restrict__ inv_out, const float* __restrict__ inv_in,
    float* __restrict__ Zg, float* __restrict__ accDh,
    __half* __restrict__ PH_f, __half* __restrict__ PH_b, int N) {
  int t = blockIdx.x * blockDim.x + threadIdx.x;
  int n = t >> 2, sub = t & 3;
  if (n >= N) return;
  int dirb = sub >> 1, grp = sub & 1;
  const int* rs  = dirb ? rs_b : rs_f;
  const int* adj = dirb ? adj_b : adj_f;
  const __half* Q2 = dirb ? Q2_b : Q2_f;
  float a[5];
  #pragma unroll
  for (int c = 0; c < 5; c++) a[c] = 0.f;
  int i0 = rs[n], i1 = rs[n + 1];
  for (int i = i0; i < i1; i++) {
    int e = ntli(adj + i);
    float w = qdec(((unsigned)e) >> 17);
    const unsigned* row =
        (const unsigned*)(Q2 + (size_t)(e & 0x1FFFF) * 12) + grp * 3;
    unsigned u0 = row[0], u1 = row[1], u2 = row[2];
    float2 f0 = uph2(u0), f1 = uph2(u1), f2 = uph2(u2);
    a[0] = fmaf(w, f0.x, a[0]); a[1] = fmaf(w, f0.y, a[1]);
    a[2] = fmaf(w, f1.x, a[2]); a[3] = fmaf(w, f1.y, a[3]);
    a[4] = fmaf(w, f2.x, a[4]);
  }
  float b[5];
  #pragma unroll
  for (int c = 0; c < 5; c++) {
    a[c] += __shfl_xor(a[c], 2);      // sum fwd+bwd directions
    b[c]  = __shfl_xor(a[c], 1);      // other channel group's sum
  }
  float zA[5], rA[5];
  #pragma unroll
  for (int c = 0; c < 5; c++) {
    zA[c] = grp ? b[c] : a[c];
    rA[c] = grp ? a[c] : b[c];
  }

  float r[5], zv[5];
  #pragma unroll
  for (int o = 0; o < 5; o++) {
    float zp = accDz[(size_t)n * 5 + o] + Q1_f[(size_t)n * 10 + o] +
               Q1_b[(size_t)n * 10 + o] + 2.f * zA[o];
    float rp = accDr[(size_t)n * 5 + o] + Q1_f[(size_t)n * 10 + 5 + o] +
               Q1_b[(size_t)n * 10 + 5 + o] + 2.f * rA[o];
    zv[o] = 1.f / (1.f + __expf(-zp));
    r[o]  = 1.f / (1.f + __expf(-rp));
  }
  if (sub == 0) {
    #pragma unroll
    for (int o = 0; o < 5; o++) Zg[(size_t)n * 5 + o] = zv[o];
  }
  float hr[5];
  #pragma unroll
  for (int o = 0; o < 5; o++) hr[o] = h1[(size_t)n * 5 + o] * r[o];

  float sOut = inv_out[n], sIn = inv_in[n];
  int c0 = (sub == 0) ? 0 : 7 + 6 * (sub - 1);
  int c1 = (sub == 0) ? 7 : c0 + 6;
  for (int c = c0; c < c1; c++) {
    float acc = __half2float(accCx[(size_t)n * 25 + c]);
    #pragma unroll
    for (int o = 0; o < 5; o++) acc = fmaf(hr[o], WpackC[(F_IN + o) * 25 + c], acc);
    if (c < 5)       accDh[(size_t)n * 5 + c] = acc + bh[c];
    else if (c < 10) PH_f[(size_t)n * 12 + (c - 5)] = __float2half(acc * sOut);
    else if (c < 15) PH_f[(size_t)n * 12 + 6 + (c - 10)] = __float2half(acc * sOut);
    else if (c < 20) PH_b[(size_t)n * 12 + (c - 15)] = __float2half(acc * sIn);
    else             PH_b[(size_t)n * 12 + 6 + (c - 20)] = __float2half(acc * sIn);
  }
}

// ---------------------------------------------------------------------------
// P3: 1-hop h, DIR-PER-BLOCK; paired-lane split over PH's two 5-col groups
// (h0-4 Fh1 -> Q1h fp32; h6-10 Fh2 -> Q2h fp16, pre-scaled).
// ---------------------------------------------------------------------------
__global__ __launch_bounds__(256) void p3_kernel(
    const int* __restrict__ rs_f, const int* __restrict__ rs_b,
    const int* __restrict__ adj_f, const int* __restrict__ adj_b,
    const __half* __restrict__ PH_f, const __half* __restrict__ PH_b,
    const float* __restrict__ inv_out, const float* __restrict__ inv_in,
    float* __restrict__ Q1h_f, float* __restrict__ Q1h_b,
    __half* __restrict__ Q2h_f, __half* __restrict__ Q2h_b, int N) {
  int dir = blockIdx.x & 1;
  int idx = (blockIdx.x >> 1) * 256 + threadIdx.x;
  if (idx >= 2 * N) return;
  int n = idx >> 1, half = idx & 1;
  const int* rs  = dir ? rs_b : rs_f;
  const int* adj = dir ? adj_b : adj_f;
  const __half* PH = dir ? PH_b : PH_f;
  int i0 = rs[n], i1 = rs[n + 1];
  float acc[5];
  #pragma unroll
  for (int c = 0; c < 5; c++) acc[c] = 0.f;
  for (int i = i0; i < i1; i++) {
    int a = ntli(adj + i);
    float w = qdec(((unsigned)a) >> 17);
    const unsigned* row =
        (const unsigned*)(PH + (size_t)(a & 0x1FFFF) * 12) + half * 3;
    unsigned u0 = row[0], u1 = row[1], u2 = row[2];
    float2 f0 = uph2(u0), f1 = uph2(u1), f2 = uph2(u2);
    acc[0] = fmaf(w, f0.x, acc[0]); acc[1] = fmaf(w, f0.y, acc[1]);
    acc[2] = fmaf(w, f1.x, acc[2]); acc[3] = fmaf(w, f1.y, acc[3]);
    acc[4] = fmaf(w, f2.x, acc[4]);
  }
  if (!half) {
    float* q = (dir ? Q1h_b : Q1h_f) + (size_t)n * 5;
    #pragma unroll
    for (int c = 0; c < 5; c++) q[c] = acc[c];
  } else {
    float sc = dir ? inv_in[n] : inv_out[n];
    unsigned* q = (unsigned*)((dir ? Q2h_b : Q2h_f) + (size_t)n * 8);
    q[0] = pkh2(acc[0] * sc, acc[1] * sc);
    q[1] = pkh2(acc[2] * sc, acc[3] * sc);
    q[2] = pkh2(acc[4] * sc, 0.f);
  }
}

// ---------------------------------------------------------------------------
// P4: 2-hop h gather (fp16 Q2h, lane-split) + nodeC body -> y. 2N threads.
// ---------------------------------------------------------------------------
__global__ __launch_bounds__(256) void p4_kernel(
    const int* __restrict__ rs_f, const int* __restrict__ rs_b,
    const int* __restrict__ adj_f, const int* __restrict__ adj_b,
    const __half* __restrict__ Q2h_f, const __half* __restrict__ Q2h_b,
    const float* __restrict__ Q1h_f, const float* __restrict__ Q1h_b,
    const float* __restrict__ accDh, const float* __restrict__ Zg,
    const float* __restrict__ h1, const float* __restrict__ Wl,
    const float* __restrict__ bl, float* __restrict__ y, int N) {
  int t = blockIdx.x * blockDim.x + threadIdx.x;
  int n = t >> 1, l = t & 1;
  if (n >= N) return;
  const int* rs  = l ? rs_b : rs_f;
  const int* adj = l ? adj_b : adj_f;
  const __half* Q2h = l ? Q2h_b : Q2h_f;
  float a[5];
  #pragma unroll
  for (int c = 0; c < 5; c++) a[c] = 0.f;
  int i0 = rs[n], i1 = rs[n + 1];
  for (int i = i0; i < i1; i++) {
    int e = ntli(adj + i);
    float w = qdec(((unsigned)e) >> 17);
    const unsigned* row = (const unsigned*)(Q2h + (size_t)(e & 0x1FFFF) * 8);
    unsigned u0 = row[0], u1 = row[1], u2 = row[2];
    float2 f0 = uph2(u0), f1 = uph2(u1), f2 = uph2(u2);
    a[0] = fmaf(w, f0.x, a[0]); a[1] = fmaf(w, f0.y, a[1]);
    a[2] = fmaf(w, f1.x, a[2]); a[3] = fmaf(w, f1.y, a[3]);
    a[4] = fmaf(w, f2.x, a[4]);
  }
  #pragma unroll
  for (int c = 0; c < 5; c++) a[c] += __shfl_xor(a[c], 1);
  if (l) return;
  float acc = bl[0];
  #pragma unroll
  for (int o = 0; o < 5; o++) {
    float pre = accDh[(size_t)n * 5 + o] + Q1h_f[(size_t)n * 5 + o] +
                Q1h_b[(size_t)n * 5 + o] + 2.f * a[o];
    float ht = tanhf(pre);
    float z = Zg[(size_t)n * 5 + o];
    float H = z * h1[(size_t)n * 5 + o] + (1.f - z) * ht;
    acc += fmaxf(H, 0.f) * Wl[o];
  }
  y[n] = acc;
}

// ---------------------------------------------------------------------------
extern "C" void kernel_launch(void* const* d_in, const int* in_sizes, int n_in,
                              void* d_out, int out_size, void* d_ws, size_t ws_size,
                              hipStream_t stream) {
  const float* x  = (const float*)d_in[0];
  const int*   ei = (const int*)d_in[1];
  const float* ew = (const float*)d_in[2];
  const float* W1 = (const float*)d_in[3];
  const float* b1 = (const float*)d_in[4];
  const float* W2 = (const float*)d_in[5];
  const float* b2 = (const float*)d_in[6];
  const float* Wz = (const float*)d_in[7];
  const float* bz = (const float*)d_in[8];
  const float* Wr = (const float*)d_in[9];
  const float* br = (const float*)d_in[10];
  const float* Wh = (const float*)d_in[11];
  const float* bh = (const float*)d_in[12];
  const float* Wl = (const float*)d_in[13];
  const float* bl = (const float*)d_in[14];

  const int N = in_sizes[0] / F_IN;
  const int E = in_sizes[2];
  const int nbuck = ((N - 1) >> BSH) + 1;   // N <= 131072 assumed

  float* out = (float*)d_out;
  float* y_out  = out;          // [N]
  float* wf_out = out + N;      // [E]  == output A

  // Workspace layout (4-byte words; 8B alignment maintained for packed loads)
  float* W = (float*)d_ws;
  size_t o = 0;
  int* bcnt_f  = (int*)(W + o); o += MAXB;       // zeroed as one block
  int* bcnt_b  = (int*)(W + o); o += MAXB;
  int* bbase_f = (int*)(W + o); o += MAXB + 2;
  int* bbase_b = (int*)(W + o); o += MAXB + 2;
  int* bcur_f  = (int*)(W + o); o += MAXB;
  int* bcur_b  = (int*)(W + o); o += MAXB;
  int* rs_f    = (int*)(W + o); o += (size_t)N + 1;
  int* rs_b    = (int*)(W + o); o += (size_t)N + 1;
  float* inv_out = W + o; o += N;
  float* inv_in  = W + o; o += N;
  int* adj_f   = (int*)(W + o); o += (size_t)E;
  int* adj_b   = (int*)(W + o); o += (size_t)E;
  float* h1    = W + o; o += (size_t)5 * N;
  float* accDz = W + o; o += (size_t)5 * N;
  float* accDr = W + o; o += (size_t)5 * N;
  float* accDh = W + o; o += (size_t)5 * N;
  float* Zg    = W + o; o += (size_t)5 * N;
  __half* accCx = (__half*)(W + o); o += (size_t)13 * N;  // [N][25] fp16
  o = (o + 1) & ~(size_t)1;                 // 8B align
  size_t prop0 = o;                         // binned aliases from here
  __half* PA_f = (__half*)(W + o); o += (size_t)10 * N;   // [N][20] fp16
  __half* PA_b = (__half*)(W + o); o += (size_t)10 * N;
  float* Q1_f  = W + o; o += (size_t)10 * N;              // [N][10] fp32
  float* Q1_b  = W + o; o += (size_t)10 * N;
  __half* Q2_f = (__half*)(W + o); o += (size_t)6 * N;    // [N][12] fp16
  __half* Q2_b = (__half*)(W + o); o += (size_t)6 * N;
  __half* PH_f = (__half*)(W + o); o += (size_t)6 * N;    // [N][12] fp16
  __half* PH_b = (__half*)(W + o); o += (size_t)6 * N;
  float* Q1h_f = W + o; o += (size_t)5 * N;               // [N][5] fp32
  float* Q1h_b = W + o; o += (size_t)5 * N;
  o = (o + 1) & ~(size_t)1;
  __half* Q2h_f = (__half*)(W + o); o += (size_t)4 * N;   // [N][8] fp16
  __half* Q2h_b = (__half*)(W + o); o += (size_t)4 * N;
  float* WpackA = W + o; o += 2000;
  float* WpackC = W + o; o += 1000;

  // binned scratch aliases the prop region (consumed by passC before nodeA
  // writes anything there); needs 4E words <= 80N words.
  int2* binned_f = (int2*)(W + prop0);
  int2* binned_b = binned_f + E;

  const int NB2 = (2 * N + 255) / 256;
  const int NB4 = (4 * N + 255) / 256;
  const int NBd = 2 * ((2 * N + 255) / 256);   // dir-per-block grids
  const int NBn = (N + 63) / 64;

  // 1. packed weights
  prep_weights<<<8, 256, 0, stream>>>(Wz, Wr, Wh, WpackA, WpackC);

  // 2. CSR build
  hipMemsetAsync(bcnt_f, 0, 2 * MAXB * sizeof(int), stream);
  hist_kernel<<<512, 256, 0, stream>>>(ei, bcnt_f, bcnt_b, E);
  scanb_kernel<<<1, MAXB, 0, stream>>>(bcnt_f, bcnt_b, bbase_f, bbase_b,
                                       bcur_f, bcur_b, rs_f, rs_b,
                                       nbuck, N, E);
  passB_kernel<<<256, 512, 0, stream>>>(ei, ew, bcur_f, bcur_b,
                                        binned_f, binned_b, E);
  passC_kernel<<<dim3(nbuck, 2), 256, 0, stream>>>(
      binned_f, binned_b, bbase_f, bbase_b, adj_f, adj_b,
      rs_f, rs_b, inv_in, inv_out, N);
  wfout_kernel<<<1024, 256, 0, stream>>>(ei, ew, inv_out, wf_out, E);

  // 3. node phase A
  nodeA_kernel<<<NBn, 256, 0, stream>>>(x, W1, b1, W2, b2, bz, br, WpackA,
                                        WpackC, inv_out, inv_in,
                                        h1, accDz, accDr, PA_f, PA_b,
                                        accCx, N);

  // 4. fused propagation + gate phases
  p1_kernel<<<NBd, 256, 0, stream>>>(rs_f, rs_b, adj_f, adj_b, PA_f, PA_b,
                                     inv_out, inv_in, Q1_f, Q1_b, Q2_f, Q2_b, N);
  p2_kernel<<<NB4, 256, 0, stream>>>(rs_f, rs_b, adj_f, adj_b, Q2_f, Q2_b,
                                     Q1_f, Q1_b, accDz, accDr, accCx, h1, bh,
                                     WpackC, inv_out, inv_in,
                                     Zg, accDh, PH_f, PH_b, N);
  p3_kernel<<<NBd, 256, 0, stream>>>(rs_f, rs_b, adj_f, adj_b, PH_f, PH_b,
                                     inv_out, inv_in, Q1h_f, Q1h_b,
                                     Q2h_f, Q2h_b, N);
  p4_kernel<<<NB2, 256, 0, stream>>>(rs_f, rs_b, adj_f, adj_b, Q2h_f, Q2h_b,
                                     Q1h_f, Q1h_b, accDh, Zg, h1, Wl, bl,
                                     y_out, N);
}

// Round 9
// 398.667 us; speedup vs baseline: 1.3380x; 1.1718x over previous
//
#include <hip/hip_runtime.h>
#include <hip/hip_fp16.h>

#define F_IN 35
#define F_OUT 5
#define HID 100
#define BSH 8              // 256 node-ids per bucket
#define BMSK 255
#define MAXB 512           // max buckets (requires N <= 131072)

// 15-bit relative float for w in (0,1]: 4-bit exp, 11-bit mantissa.
__device__ __forceinline__ unsigned qenc(float w) {
  unsigned b = __float_as_uint(w);
  int e = 127 - (int)((b >> 23) & 0xFF);
  unsigned m = (b >> 12) & 0x7FFu;
  if (e < 0) { e = 0; m = 0; }
  if (e > 15) { e = 15; m = 0; }
  return ((unsigned)e << 11) | m;
}
__device__ __forceinline__ float qdec(unsigned q) {
  return __uint_as_float(((127u - (q >> 11)) << 23) | ((q & 0x7FFu) << 12));
}

__device__ __forceinline__ float2 uph2(unsigned u) {
  __half2 h = *reinterpret_cast<const __half2*>(&u);
  return __half22float2(h);
}
__device__ __forceinline__ unsigned pkh2(float a, float b) {
  __half2 h = __floats2half2_rn(a, b);
  return *reinterpret_cast<const unsigned*>(&h);
}

// Non-temporal LOADS only (edge lists, adjacency). NT STORES forbidden
// (round-7: 6x write amplification on strided stores).
__device__ __forceinline__ int ntli(const int* p) {
  return __builtin_nontemporal_load(p);
}
__device__ __forceinline__ float ntlf(const float* p) {
  return __builtin_nontemporal_load(p);
}
__device__ __forceinline__ void ntsf(float* p, float v) {
  __builtin_nontemporal_store(v, p);   // ONLY for coalesced final output
}

// ---------------------------------------------------------------------------
// Weight prep.
// WpackA [40x50]: 0-4 Dz, 5-9 Dr, 10-14 Fz1, 15-19 Fr1, 20-24 Fz2, 25-29 Fr2,
//                 30-34 Bz1, 35-39 Br1, 40-44 Bz2, 45-49 Br2
// WpackC [40x25]: 0-4 Dh, 5-9 Fh1, 10-14 Fh2, 15-19 Bh1, 20-24 Bh2
// ---------------------------------------------------------------------------
__global__ __launch_bounds__(256) void prep_weights(
    const float* __restrict__ Wz, const float* __restrict__ Wr,
    const float* __restrict__ Wh,
    float* __restrict__ WpackA, float* __restrict__ WpackC) {
  int t = blockIdx.x * blockDim.x + threadIdx.x;
  if (t < 40 * 50) {
    int i = t / 50, c = t % 50;
    auto W = [&](const float* Wp, int d, int k, int o) {
      return Wp[((d * 3 + k) * 40 + i) * 5 + o];
    };
    float v;
    if (c < 5)       v = W(Wz,0,0,c)    + W(Wz,1,0,c)    - W(Wz,0,2,c)    - W(Wz,1,2,c);
    else if (c < 10) v = W(Wr,0,0,c-5)  + W(Wr,1,0,c-5)  - W(Wr,0,2,c-5)  - W(Wr,1,2,c-5);
    else if (c < 15) v = W(Wz,0,1,c-10);
    else if (c < 20) v = W(Wr,0,1,c-15);
    else if (c < 25) v = W(Wz,0,2,c-20);
    else if (c < 30) v = W(Wr,0,2,c-25);
    else if (c < 35) v = W(Wz,1,1,c-30);
    else if (c < 40) v = W(Wr,1,1,c-35);
    else if (c < 45) v = W(Wz,1,2,c-40);
    else             v = W(Wr,1,2,c-45);
    WpackA[i * 50 + c] = v;
  }
  if (t < 40 * 25) {
    int i = t / 25, c = t % 25;
    auto W = [&](const float* Wp, int d, int k, int o) {
      return Wp[((d * 3 + k) * 40 + i) * 5 + o];
    };
    float v;
    if (c < 5)       v = W(Wh,0,0,c)    + W(Wh,1,0,c)    - W(Wh,0,2,c)    - W(Wh,1,2,c);
    else if (c < 10) v = W(Wh,0,1,c-5);
    else if (c < 15) v = W(Wh,0,2,c-10);
    else if (c < 20) v = W(Wh,1,1,c-15);
    else             v = W(Wh,1,2,c-20);
    WpackC[i * 25 + c] = v;
  }
}

// ---------------------------------------------------------------------------
// Build 1: bucket histograms (LDS pre-aggregated).
// ---------------------------------------------------------------------------
__global__ __launch_bounds__(256) void hist_kernel(
    const int* __restrict__ ei, int* __restrict__ bcnt_f,
    int* __restrict__ bcnt_b, int E) {
  __shared__ int h[2 * MAXB];
  for (int j = threadIdx.x; j < 2 * MAXB; j += blockDim.x) h[j] = 0;
  __syncthreads();
  for (int e = blockIdx.x * blockDim.x + threadIdx.x; e < E;
       e += gridDim.x * blockDim.x) {
    int s = ntli(ei + e), d = ntli(ei + E + e);
    atomicAdd(&h[d >> BSH], 1);
    atomicAdd(&h[MAXB + (s >> BSH)], 1);
  }
  __syncthreads();
  for (int j = threadIdx.x; j < 2 * MAXB; j += blockDim.x) {
    int v = h[j];
    if (v) {
      if (j < MAXB) atomicAdd(&bcnt_f[j], v);
      else          atomicAdd(&bcnt_b[j - MAXB], v);
    }
  }
}

// ---------------------------------------------------------------------------
// Build 2: bucket exclusive scan -> bases + cursors; rs[N]=E sentinels.
// ---------------------------------------------------------------------------
__global__ __launch_bounds__(512) void scanb_kernel(
    const int* __restrict__ bcnt_f, const int* __restrict__ bcnt_b,
    int* __restrict__ bbase_f, int* __restrict__ bbase_b,
    int* __restrict__ bcur_f, int* __restrict__ bcur_b,
    int* __restrict__ rs_f, int* __restrict__ rs_b,
    int nbuck, int N, int E) {
  __shared__ int s0[MAXB], s1[MAXB];
  int t = threadIdx.x;
  s0[t] = (t < nbuck) ? bcnt_f[t] : 0;
  s1[t] = (t < nbuck) ? bcnt_b[t] : 0;
  __syncthreads();
  for (int off = 1; off < MAXB; off <<= 1) {
    int a = (t >= off) ? s0[t - off] : 0;
    int b = (t >= off) ? s1[t - off] : 0;
    __syncthreads();
    s0[t] += a; s1[t] += b;
    __syncthreads();
  }
  bbase_f[t + 1] = s0[t];
  bbase_b[t + 1] = s1[t];
  bcur_f[t] = t ? s0[t - 1] : 0;
  bcur_b[t] = t ? s1[t - 1] : 0;
  if (t == 0) { bbase_f[0] = 0; bbase_b[0] = 0; rs_f[N] = E; rs_b[N] = E; }
}

// ---------------------------------------------------------------------------
// Build 3: bin edges into compact bucket regions. Item: other|keylow<<17, w.
// ---------------------------------------------------------------------------
__global__ __launch_bounds__(512) void passB_kernel(
    const int* __restrict__ ei, const float* __restrict__ w,
    int* __restrict__ bcur_f, int* __restrict__ bcur_b,
    int2* __restrict__ binned_f, int2* __restrict__ binned_b, int E) {
  __shared__ int hf[MAXB], hb[MAXB], cf[MAXB], cb_[MAXB];
  int tid = threadIdx.x;
  for (int j = tid; j < MAXB; j += blockDim.x) { hf[j] = 0; hb[j] = 0; cf[j] = 0; cb_[j] = 0; }
  __syncthreads();
  size_t c0 = (size_t)blockIdx.x * E / gridDim.x;
  size_t c1 = (size_t)(blockIdx.x + 1) * E / gridDim.x;
  for (size_t e = c0 + tid; e < c1; e += blockDim.x) {
    int s = ntli(ei + e), d = ntli(ei + E + e);
    atomicAdd(&hf[d >> BSH], 1);
    atomicAdd(&hb[s >> BSH], 1);
  }
  __syncthreads();
  for (int j = tid; j < MAXB; j += blockDim.x) {
    int v = hf[j];
    if (v) hf[j] = atomicAdd(&bcur_f[j], v);
    int u = hb[j];
    if (u) hb[j] = atomicAdd(&bcur_b[j], u);
  }
  __syncthreads();
  for (size_t e = c0 + tid; e < c1; e += blockDim.x) {
    int s = ntli(ei + e), d = ntli(ei + E + e);
    int wb = __float_as_int(ntlf(w + e));
    int bf = d >> BSH;
    int pf = hf[bf] + atomicAdd(&cf[bf], 1);
    binned_f[pf] = make_int2(s | ((d & BMSK) << 17), wb);
    int bb = s >> BSH;
    int pb = hb[bb] + atomicAdd(&cb_[bb], 1);
    binned_b[pb] = make_int2(d | ((s & BMSK) << 17), wb);
  }
}

// ---------------------------------------------------------------------------
// Build 4: per-bucket CSR finalize (degrees over DECODED quantized weights).
// dir0 (fwd, keyed by dst) -> inv_in; dir1 (bwd, keyed by src) -> inv_out.
// ---------------------------------------------------------------------------
__global__ __launch_bounds__(256) void passC_kernel(
    const int2* __restrict__ binned_f, const int2* __restrict__ binned_b,
    const int* __restrict__ bbase_f, const int* __restrict__ bbase_b,
    int* __restrict__ adj_f, int* __restrict__ adj_b,
    int* __restrict__ rs_f, int* __restrict__ rs_b,
    float* __restrict__ inv_in, float* __restrict__ inv_out, int N) {
  int dir = blockIdx.y;
  const int2* binned = dir ? binned_b : binned_f;
  const int* bbase   = dir ? bbase_b  : bbase_f;
  int* adj           = dir ? adj_b    : adj_f;
  int* rs            = dir ? rs_b     : rs_f;
  float* inv         = dir ? inv_out  : inv_in;
  int b = blockIdx.x;
  int base = bbase[b], end = bbase[b + 1];
  __shared__ int cnt[256]; __shared__ float wsum[256];
  __shared__ int loc[256]; __shared__ int cur[256];
  int tid = threadIdx.x;
  cnt[tid] = 0; wsum[tid] = 0.f; cur[tid] = 0;
  __syncthreads();
  for (int i = base + tid; i < end; i += 256) {
    int2 it = binned[i];
    int nl = (it.x >> 17) & BMSK;
    atomicAdd(&cnt[nl], 1);
    atomicAdd(&wsum[nl], qdec(qenc(__int_as_float(it.y))));
  }
  __syncthreads();
  int v = cnt[tid];
  loc[tid] = v;
  __syncthreads();
  for (int off = 1; off < 256; off <<= 1) {
    int a = (tid >= off) ? loc[tid - off] : 0;
    __syncthreads();
    loc[tid] += a;
    __syncthreads();
  }
  int excl = loc[tid] - v;
  int node = (b << BSH) + tid;
  if (node < N) {
    rs[node] = base + excl;
    inv[node] = 1.f / fmaxf(wsum[tid], 1e-12f);
  }
  __syncthreads();
  loc[tid] = excl;
  __syncthreads();
  for (int i = base + tid; i < end; i += 256) {
    int2 it = binned[i];
    int nl = (it.x >> 17) & BMSK;
    int p = base + loc[nl] + atomicAdd(&cur[nl], 1);
    adj[p] = (it.x & 0x1FFFF) | (int)(qenc(__int_as_float(it.y)) << 17);
  }
}

// ---------------------------------------------------------------------------
// Output A: w_fwd = ew * inv_out[src]  (nt store OK: coalesced final output)
// ---------------------------------------------------------------------------
__global__ __launch_bounds__(256) void wfout_kernel(
    const int* __restrict__ ei, const float* __restrict__ ew,
    const float* __restrict__ inv_out, float* __restrict__ wf, int E) {
  for (int e = blockIdx.x * blockDim.x + threadIdx.x; e < E;
       e += gridDim.x * blockDim.x)
    ntsf(wf + e, ntlf(ew + e) * inv_out[ntli(ei + e)]);
}

// ---------------------------------------------------------------------------
// Node phase A: block = 4 waves = 64 nodes; wave-uniform weight indexing.
// Emits fp16 PA (p1 gather input, pre-scaled) and fp16 accCx = x@WpackC[0:35].
// ---------------------------------------------------------------------------
__global__ __launch_bounds__(256) void nodeA_kernel(
    const float* __restrict__ x,
    const float* __restrict__ W1, const float* __restrict__ b1,
    const float* __restrict__ W2, const float* __restrict__ b2,
    const float* __restrict__ bz, const float* __restrict__ br,
    const float* __restrict__ WpackA, const float* __restrict__ WpackC,
    const float* __restrict__ inv_out, const float* __restrict__ inv_in,
    float* __restrict__ h1, float* __restrict__ accDz,
    float* __restrict__ accDr, __half* __restrict__ PA_f,
    __half* __restrict__ PA_b, __half* __restrict__ accCx, int N) {
  __shared__ float part[4][64][5];
  int tid = threadIdx.x;
  int lane = tid & 63;
  int q = __builtin_amdgcn_readfirstlane(tid >> 6);
  int n = blockIdx.x * 64 + lane;
  bool act = n < N;
  float xv[40];
  const float* xr = x + (size_t)n * F_IN;
  #pragma unroll
  for (int i = 0; i < F_IN; i++) xv[i] = act ? xr[i] : 0.f;

  float h5[5] = {0.f, 0.f, 0.f, 0.f, 0.f};
  int hbase = q * 25;
  for (int k = 0; k < 25; k++) {
    int hh = hbase + k;
    float a = b1[hh];
    #pragma unroll
    for (int i = 0; i < F_IN; i++) a = fmaf(xv[i], W1[i * HID + hh], a);
    a = fmaxf(a, 0.f);
    #pragma unroll
    for (int o = 0; o < 5; o++) h5[o] = fmaf(a, W2[hh * 5 + o], h5[o]);
  }
  #pragma unroll
  for (int o = 0; o < 5; o++) part[q][lane][o] = h5[o];
  __syncthreads();
  #pragma unroll
  for (int o = 0; o < 5; o++) {
    h5[o] = part[0][lane][o] + part[1][lane][o] + part[2][lane][o] +
            part[3][lane][o] + b2[o];
    xv[F_IN + o] = h5[o];
  }
  if (!act) return;
  if (q == 0) {
    #pragma unroll
    for (int o = 0; o < 5; o++) h1[(size_t)n * 5 + o] = h5[o];
  }
  float sOut = inv_out[n], sIn = inv_in[n];
  // 75 columns: 0-49 WpackA (XH), 50-74 WpackC[0:35] (x only)
  int c0 = q * 19, c1 = min(c0 + 19, 75);
  for (int c = c0; c < c1; c++) {
    float a = 0.f;
    if (c < 50) {
      #pragma unroll
      for (int i = 0; i < 40; i++) a = fmaf(xv[i], WpackA[i * 50 + c], a);
    } else {
      #pragma unroll
      for (int i = 0; i < F_IN; i++) a = fmaf(xv[i], WpackC[i * 25 + (c - 50)], a);
    }
    if (c < 5)       accDz[(size_t)n * 5 + c] = a + bz[c];
    else if (c < 10) accDr[(size_t)n * 5 + (c - 5)] = a + br[c - 5];
    else if (c < 30) PA_f[(size_t)n * 20 + (c - 10)] = __float2half(a * sOut);
    else if (c < 50) PA_b[(size_t)n * 20 + (c - 30)] = __float2half(a * sIn);
    else             accCx[(size_t)n * 25 + (c - 50)] = __float2half(a);
  }
}

// ---------------------------------------------------------------------------
// P1: 1-hop fwd+bwd. DIR-PER-BLOCK. Paired lanes share (node,dir), 10-col
// halves. 4-wide BATCHED gather loop: issue 4 adj loads, then all 20 gather
// dwords, then unpack/FMA — overlaps 4 gather latencies.
// half0 -> Q1 fp32; half1 -> Q2 fp16 [N][12] (5+pad groups, pre-scaled).
// ---------------------------------------------------------------------------
__global__ __launch_bounds__(256) void p1_kernel(
    const int* __restrict__ rs_f, const int* __restrict__ rs_b,
    const int* __restrict__ adj_f, const int* __restrict__ adj_b,
    const __half* __restrict__ PA_f, const __half* __restrict__ PA_b,
    const float* __restrict__ inv_out, const float* __restrict__ inv_in,
    float* __restrict__ Q1_f, float* __restrict__ Q1_b,
    __half* __restrict__ Q2_f, __half* __restrict__ Q2_b, int N) {
  int dir = blockIdx.x & 1;
  int idx = (blockIdx.x >> 1) * 256 + threadIdx.x;
  if (idx >= 2 * N) return;
  int n = idx >> 1, half = idx & 1;
  const int* rs  = dir ? rs_b : rs_f;
  const int* adj = dir ? adj_b : adj_f;
  const __half* PA = dir ? PA_b : PA_f;
  int i0 = rs[n], i1 = rs[n + 1];
  float acc[10];
  #pragma unroll
  for (int c = 0; c < 10; c++) acc[c] = 0.f;
  int i = i0;
  for (; i + 4 <= i1; i += 4) {
    int a0 = ntli(adj + i),     a1 = ntli(adj + i + 1),
        a2 = ntli(adj + i + 2), a3 = ntli(adj + i + 3);
    const unsigned* r0 = (const unsigned*)(PA + (size_t)(a0 & 0x1FFFF) * 20) + half * 5;
    const unsigned* r1 = (const unsigned*)(PA + (size_t)(a1 & 0x1FFFF) * 20) + half * 5;
    const unsigned* r2 = (const unsigned*)(PA + (size_t)(a2 & 0x1FFFF) * 20) + half * 5;
    const unsigned* r3 = (const unsigned*)(PA + (size_t)(a3 & 0x1FFFF) * 20) + half * 5;
    unsigned u0[5], u1[5], u2[5], u3[5];
    #pragma unroll
    for (int k = 0; k < 5; k++) u0[k] = r0[k];
    #pragma unroll
    for (int k = 0; k < 5; k++) u1[k] = r1[k];
    #pragma unroll
    for (int k = 0; k < 5; k++) u2[k] = r2[k];
    #pragma unroll
    for (int k = 0; k < 5; k++) u3[k] = r3[k];
    float w0 = qdec(((unsigned)a0) >> 17), w1 = qdec(((unsigned)a1) >> 17),
          w2 = qdec(((unsigned)a2) >> 17), w3 = qdec(((unsigned)a3) >> 17);
    #pragma unroll
    for (int k = 0; k < 5; k++) {
      float2 f0 = uph2(u0[k]), f1 = uph2(u1[k]), f2 = uph2(u2[k]), f3 = uph2(u3[k]);
      acc[2*k]   = fmaf(w0, f0.x, acc[2*k]);   acc[2*k+1] = fmaf(w0, f0.y, acc[2*k+1]);
      acc[2*k]   = fmaf(w1, f1.x, acc[2*k]);   acc[2*k+1] = fmaf(w1, f1.y, acc[2*k+1]);
      acc[2*k]   = fmaf(w2, f2.x, acc[2*k]);   acc[2*k+1] = fmaf(w2, f2.y, acc[2*k+1]);
      acc[2*k]   = fmaf(w3, f3.x, acc[2*k]);   acc[2*k+1] = fmaf(w3, f3.y, acc[2*k+1]);
    }
  }
  for (; i < i1; i++) {
    int a = ntli(adj + i);
    float w = qdec(((unsigned)a) >> 17);
    const unsigned* row = (const unsigned*)(PA + (size_t)(a & 0x1FFFF) * 20) + half * 5;
    #pragma unroll
    for (int k = 0; k < 5; k++) {
      float2 f = uph2(row[k]);
      acc[2*k] = fmaf(w, f.x, acc[2*k]); acc[2*k+1] = fmaf(w, f.y, acc[2*k+1]);
    }
  }
  if (!half) {
    float* q = (dir ? Q1_b : Q1_f) + (size_t)n * 10;
    #pragma unroll
    for (int c = 0; c < 10; c++) q[c] = acc[c];
  } else {
    float sc = dir ? inv_in[n] : inv_out[n];
    unsigned* q = (unsigned*)((dir ? Q2_b : Q2_f) + (size_t)n * 12);
    q[0] = pkh2(acc[0] * sc, acc[1] * sc);
    q[1] = pkh2(acc[2] * sc, acc[3] * sc);
    q[2] = pkh2(acc[4] * sc, 0.f);
    q[3] = pkh2(acc[5] * sc, acc[6] * sc);
    q[4] = pkh2(acc[7] * sc, acc[8] * sc);
    q[5] = pkh2(acc[9] * sc, 0.f);
  }
}

// ---------------------------------------------------------------------------
// P2a: 2-hop gather, DIR-PER-BLOCK (single-dir Q2 = 2.88MB, L2-resident per
// XCD). Paired lanes = (node, group). 8-wide batched gather (24 dwords in
// flight). Writes per-direction partials G[dir][N][10] fp32 (node-local).
// ---------------------------------------------------------------------------
__global__ __launch_bounds__(256) void p2a_kernel(
    const int* __restrict__ rs_f, const int* __restrict__ rs_b,
    const int* __restrict__ adj_f, const int* __restrict__ adj_b,
    const __half* __restrict__ Q2_f, const __half* __restrict__ Q2_b,
    float* __restrict__ G_f, float* __restrict__ G_b, int N) {
  int dir = blockIdx.x & 1;
  int idx = (blockIdx.x >> 1) * 256 + threadIdx.x;
  if (idx >= 2 * N) return;
  int n = idx >> 1, grp = idx & 1;
  const int* rs  = dir ? rs_b : rs_f;
  const int* adj = dir ? adj_b : adj_f;
  const __half* Q2 = dir ? Q2_b : Q2_f;
  int i0 = rs[n], i1 = rs[n + 1];
  float a[5];
  #pragma unroll
  for (int c = 0; c < 5; c++) a[c] = 0.f;
  int i = i0;
  for (; i + 8 <= i1; i += 8) {
    int e[8];
    #pragma unroll
    for (int k = 0; k < 8; k++) e[k] = ntli(adj + i + k);
    unsigned u[8][3];
    #pragma unroll
    for (int k = 0; k < 8; k++) {
      const unsigned* row =
          (const unsigned*)(Q2 + (size_t)(e[k] & 0x1FFFF) * 12) + grp * 3;
      u[k][0] = row[0]; u[k][1] = row[1]; u[k][2] = row[2];
    }
    #pragma unroll
    for (int k = 0; k < 8; k++) {
      float w = qdec(((unsigned)e[k]) >> 17);
      float2 f0 = uph2(u[k][0]), f1 = uph2(u[k][1]), f2 = uph2(u[k][2]);
      a[0] = fmaf(w, f0.x, a[0]); a[1] = fmaf(w, f0.y, a[1]);
      a[2] = fmaf(w, f1.x, a[2]); a[3] = fmaf(w, f1.y, a[3]);
      a[4] = fmaf(w, f2.x, a[4]);
    }
  }
  for (; i < i1; i++) {
    int e = ntli(adj + i);
    float w = qdec(((unsigned)e) >> 17);
    const unsigned* row =
        (const unsigned*)(Q2 + (size_t)(e & 0x1FFFF) * 12) + grp * 3;
    float2 f0 = uph2(row[0]), f1 = uph2(row[1]), f2 = uph2(row[2]);
    a[0] = fmaf(w, f0.x, a[0]); a[1] = fmaf(w, f0.y, a[1]);
    a[2] = fmaf(w, f1.x, a[2]); a[3] = fmaf(w, f1.y, a[3]);
    a[4] = fmaf(w, f2.x, a[4]);
  }
  float* g = (dir ? G_b : G_f) + (size_t)n * 10 + grp * 5;
  #pragma unroll
  for (int c = 0; c < 5; c++) g[c] = a[c];
}

// ---------------------------------------------------------------------------
// P2b: nodeB body (streaming only). zA/rA = G_f + G_b; gates; XHr epilogue
// (accCx precomputed, only the 5-row h-part computed here). 2N threads,
// epilogue columns split 13/12 over lane pair.
// ---------------------------------------------------------------------------
__global__ __launch_bounds__(256) void p2b_kernel(
    const float* __restrict__ G_f, const float* __restrict__ G_b,
    const float* __restrict__ Q1_f, const float* __restrict__ Q1_b,
    const float* __restrict__ accDz, const float* __restrict__ accDr,
    const __half* __restrict__ accCx, const float* __restrict__ h1,
    const float* __restrict__ bh, const float* __restrict__ WpackC,
    const float* __restrict__ inv_out, const float* __restrict__ inv_in,
    float* __restrict__ Zg, float* __restrict__ accDh,
    __half* __restrict__ PH_f, __half* __restrict__ PH_b, int N) {
  int t = blockIdx.x * blockDim.x + threadIdx.x;
  int n = t >> 1, l = t & 1;
  if (n >= N) return;
  float r[5], zv[5];
  #pragma unroll
  for (int o = 0; o < 5; o++) {
    float zA = G_f[(size_t)n * 10 + o] + G_b[(size_t)n * 10 + o];
    float rA = G_f[(size_t)n * 10 + 5 + o] + G_b[(size_t)n * 10 + 5 + o];
    float zp = accDz[(size_t)n * 5 + o] + Q1_f[(size_t)n * 10 + o] +
               Q1_b[(size_t)n * 10 + o] + 2.f * zA;
    float rp = accDr[(size_t)n * 5 + o] + Q1_f[(size_t)n * 10 + 5 + o] +
               Q1_b[(size_t)n * 10 + 5 + o] + 2.f * rA;
    zv[o] = 1.f / (1.f + __expf(-zp));
    r[o]  = 1.f / (1.f + __expf(-rp));
  }
  if (l == 0) {
    #pragma unroll
    for (int o = 0; o < 5; o++) Zg[(size_t)n * 5 + o] = zv[o];
  }
  float hr[5];
  #pragma unroll
  for (int o = 0; o < 5; o++) hr[o] = h1[(size_t)n * 5 + o] * r[o];

  float sOut = inv_out[n], sIn = inv_in[n];
  int c0 = l ? 13 : 0, c1 = l ? 25 : 13;
  for (int c = c0; c < c1; c++) {
    float acc = __half2float(accCx[(size_t)n * 25 + c]);
    #pragma unroll
    for (int o = 0; o < 5; o++) acc = fmaf(hr[o], WpackC[(F_IN + o) * 25 + c], acc);
    if (c < 5)       accDh[(size_t)n * 5 + c] = acc + bh[c];
    else if (c < 10) PH_f[(size_t)n * 12 + (c - 5)] = __float2half(acc * sOut);
    else if (c < 15) PH_f[(size_t)n * 12 + 6 + (c - 10)] = __float2half(acc * sOut);
    else if (c < 20) PH_b[(size_t)n * 12 + (c - 15)] = __float2half(acc * sIn);
    else             PH_b[(size_t)n * 12 + 6 + (c - 20)] = __float2half(acc * sIn);
  }
}

// ---------------------------------------------------------------------------
// P3: 1-hop h, DIR-PER-BLOCK; paired-lane split over PH's two 5-col groups.
// 8-wide batched gather. (h0-4 -> Q1h fp32; h6-10 -> Q2h fp16 pre-scaled.)
// ---------------------------------------------------------------------------
__global__ __launch_bounds__(256) void p3_kernel(
    const int* __restrict__ rs_f, const int* __restrict__ rs_b,
    const int* __restrict__ adj_f, const int* __restrict__ adj_b,
    const __half* __restrict__ PH_f, const __half* __restrict__ PH_b,
    const float* __restrict__ inv_out, const float* __restrict__ inv_in,
    float* __restrict__ Q1h_f, float* __restrict__ Q1h_b,
    __half* __restrict__ Q2h_f, __half* __restrict__ Q2h_b, int N) {
  int dir = blockIdx.x & 1;
  int idx = (blockIdx.x >> 1) * 256 + threadIdx.x;
  if (idx >= 2 * N) return;
  int n = idx >> 1, half = idx & 1;
  const int* rs  = dir ? rs_b : rs_f;
  const int* adj = dir ? adj_b : adj_f;
  const __half* PH = dir ? PH_b : PH_f;
  int i0 = rs[n], i1 = rs[n + 1];
  float acc[5];
  #pragma unroll
  for (int c = 0; c < 5; c++) acc[c] = 0.f;
  int i = i0;
  for (; i + 8 <= i1; i += 8) {
    int e[8];
    #pragma unroll
    for (int k = 0; k < 8; k++) e[k] = ntli(adj + i + k);
    unsigned u[8][3];
    #pragma unroll
    for (int k = 0; k < 8; k++) {
      const unsigned* row =
          (const unsigned*)(PH + (size_t)(e[k] & 0x1FFFF) * 12) + half * 3;
      u[k][0] = row[0]; u[k][1] = row[1]; u[k][2] = row[2];
    }
    #pragma unroll
    for (int k = 0; k < 8; k++) {
      float w = qdec(((unsigned)e[k]) >> 17);
      float2 f0 = uph2(u[k][0]), f1 = uph2(u[k][1]), f2 = uph2(u[k][2]);
      acc[0] = fmaf(w, f0.x, acc[0]); acc[1] = fmaf(w, f0.y, acc[1]);
      acc[2] = fmaf(w, f1.x, acc[2]); acc[3] = fmaf(w, f1.y, acc[3]);
      acc[4] = fmaf(w, f2.x, acc[4]);
    }
  }
  for (; i < i1; i++) {
    int a = ntli(adj + i);
    float w = qdec(((unsigned)a) >> 17);
    const unsigned* row =
        (const unsigned*)(PH + (size_t)(a & 0x1FFFF) * 12) + half * 3;
    float2 f0 = uph2(row[0]), f1 = uph2(row[1]), f2 = uph2(row[2]);
    acc[0] = fmaf(w, f0.x, acc[0]); acc[1] = fmaf(w, f0.y, acc[1]);
    acc[2] = fmaf(w, f1.x, acc[2]); acc[3] = fmaf(w, f1.y, acc[3]);
    acc[4] = fmaf(w, f2.x, acc[4]);
  }
  if (!half) {
    float* q = (dir ? Q1h_b : Q1h_f) + (size_t)n * 5;
    #pragma unroll
    for (int c = 0; c < 5; c++) q[c] = acc[c];
  } else {
    float sc = dir ? inv_in[n] : inv_out[n];
    unsigned* q = (unsigned*)((dir ? Q2h_b : Q2h_f) + (size_t)n * 8);
    q[0] = pkh2(acc[0] * sc, acc[1] * sc);
    q[1] = pkh2(acc[2] * sc, acc[3] * sc);
    q[2] = pkh2(acc[4] * sc, 0.f);
  }
}

// ---------------------------------------------------------------------------
// P4: 2-hop h gather (fp16 Q2h, lane dir-split, 8-wide batched) + nodeC -> y.
// ---------------------------------------------------------------------------
__global__ __launch_bounds__(256) void p4_kernel(
    const int* __restrict__ rs_f, const int* __restrict__ rs_b,
    const int* __restrict__ adj_f, const int* __restrict__ adj_b,
    const __half* __restrict__ Q2h_f, const __half* __restrict__ Q2h_b,
    const float* __restrict__ Q1h_f, const float* __restrict__ Q1h_b,
    const float* __restrict__ accDh, const float* __restrict__ Zg,
    const float* __restrict__ h1, const float* __restrict__ Wl,
    const float* __restrict__ bl, float* __restrict__ y, int N) {
  int t = blockIdx.x * blockDim.x + threadIdx.x;
  int n = t >> 1, l = t & 1;
  if (n >= N) return;
  const int* rs  = l ? rs_b : rs_f;
  const int* adj = l ? adj_b : adj_f;
  const __half* Q2h = l ? Q2h_b : Q2h_f;
  float a[5];
  #pragma unroll
  for (int c = 0; c < 5; c++) a[c] = 0.f;
  int i0 = rs[n], i1 = rs[n + 1];
  int i = i0;
  for (; i + 8 <= i1; i += 8) {
    int e[8];
    #pragma unroll
    for (int k = 0; k < 8; k++) e[k] = ntli(adj + i + k);
    unsigned u[8][3];
    #pragma unroll
    for (int k = 0; k < 8; k++) {
      const unsigned* row = (const unsigned*)(Q2h + (size_t)(e[k] & 0x1FFFF) * 8);
      u[k][0] = row[0]; u[k][1] = row[1]; u[k][2] = row[2];
    }
    #pragma unroll
    for (int k = 0; k < 8; k++) {
      float w = qdec(((unsigned)e[k]) >> 17);
      float2 f0 = uph2(u[k][0]), f1 = uph2(u[k][1]), f2 = uph2(u[k][2]);
      a[0] = fmaf(w, f0.x, a[0]); a[1] = fmaf(w, f0.y, a[1]);
      a[2] = fmaf(w, f1.x, a[2]); a[3] = fmaf(w, f1.y, a[3]);
      a[4] = fmaf(w, f2.x, a[4]);
    }
  }
  for (; i < i1; i++) {
    int e = ntli(adj + i);
    float w = qdec(((unsigned)e) >> 17);
    const unsigned* row = (const unsigned*)(Q2h + (size_t)(e & 0x1FFFF) * 8);
    float2 f0 = uph2(row[0]), f1 = uph2(row[1]), f2 = uph2(row[2]);
    a[0] = fmaf(w, f0.x, a[0]); a[1] = fmaf(w, f0.y, a[1]);
    a[2] = fmaf(w, f1.x, a[2]); a[3] = fmaf(w, f1.y, a[3]);
    a[4] = fmaf(w, f2.x, a[4]);
  }
  #pragma unroll
  for (int c = 0; c < 5; c++) a[c] += __shfl_xor(a[c], 1);
  if (l) return;
  float acc = bl[0];
  #pragma unroll
  for (int o = 0; o < 5; o++) {
    float pre = accDh[(size_t)n * 5 + o] + Q1h_f[(size_t)n * 5 + o] +
                Q1h_b[(size_t)n * 5 + o] + 2.f * a[o];
    float ht = tanhf(pre);
    float z = Zg[(size_t)n * 5 + o];
    float H = z * h1[(size_t)n * 5 + o] + (1.f - z) * ht;
    acc += fmaxf(H, 0.f) * Wl[o];
  }
  y[n] = acc;
}

// ---------------------------------------------------------------------------
extern "C" void kernel_launch(void* const* d_in, const int* in_sizes, int n_in,
                              void* d_out, int out_size, void* d_ws, size_t ws_size,
                              hipStream_t stream) {
  const float* x  = (const float*)d_in[0];
  const int*   ei = (const int*)d_in[1];
  const float* ew = (const float*)d_in[2];
  const float* W1 = (const float*)d_in[3];
  const float* b1 = (const float*)d_in[4];
  const float* W2 = (const float*)d_in[5];
  const float* b2 = (const float*)d_in[6];
  const float* Wz = (const float*)d_in[7];
  const float* bz = (const float*)d_in[8];
  const float* Wr = (const float*)d_in[9];
  const float* br = (const float*)d_in[10];
  const float* Wh = (const float*)d_in[11];
  const float* bh = (const float*)d_in[12];
  const float* Wl = (const float*)d_in[13];
  const float* bl = (const float*)d_in[14];

  const int N = in_sizes[0] / F_IN;
  const int E = in_sizes[2];
  const int nbuck = ((N - 1) >> BSH) + 1;   // N <= 131072 assumed

  float* out = (float*)d_out;
  float* y_out  = out;          // [N]
  float* wf_out = out + N;      // [E]  == output A

  // Workspace layout (4-byte words; 8B alignment maintained for packed loads)
  float* W = (float*)d_ws;
  size_t o = 0;
  int* bcnt_f  = (int*)(W + o); o += MAXB;       // zeroed as one block
  int* bcnt_b  = (int*)(W + o); o += MAXB;
  int* bbase_f = (int*)(W + o); o += MAXB + 2;
  int* bbase_b = (int*)(W + o); o += MAXB + 2;
  int* bcur_f  = (int*)(W + o); o += MAXB;
  int* bcur_b  = (int*)(W + o); o += MAXB;
  int* rs_f    = (int*)(W + o); o += (size_t)N + 1;
  int* rs_b    = (int*)(W + o); o += (size_t)N + 1;
  float* inv_out = W + o; o += N;
  float* inv_in  = W + o; o += N;
  int* adj_f   = (int*)(W + o); o += (size_t)E;
  int* adj_b   = (int*)(W + o); o += (size_t)E;
  float* h1    = W + o; o += (size_t)5 * N;
  float* accDz = W + o; o += (size_t)5 * N;
  float* accDr = W + o; o += (size_t)5 * N;
  float* accDh = W + o; o += (size_t)5 * N;
  float* Zg    = W + o; o += (size_t)5 * N;
  __half* accCx = (__half*)(W + o); o += (size_t)13 * N;  // [N][25] fp16
  o = (o + 1) & ~(size_t)1;                 // 8B align
  size_t prop0 = o;                         // binned aliases from here
  __half* PA_f = (__half*)(W + o); o += (size_t)10 * N;   // [N][20] fp16
  __half* PA_b = (__half*)(W + o); o += (size_t)10 * N;
  float* Q1_f  = W + o; o += (size_t)10 * N;              // [N][10] fp32
  float* Q1_b  = W + o; o += (size_t)10 * N;
  __half* Q2_f = (__half*)(W + o); o += (size_t)6 * N;    // [N][12] fp16
  __half* Q2_b = (__half*)(W + o); o += (size_t)6 * N;
  __half* PH_f = (__half*)(W + o); o += (size_t)6 * N;    // [N][12] fp16
  __half* PH_b = (__half*)(W + o); o += (size_t)6 * N;
  float* Q1h_f = W + o; o += (size_t)5 * N;               // [N][5] fp32
  float* Q1h_b = W + o; o += (size_t)5 * N;
  o = (o + 1) & ~(size_t)1;
  __half* Q2h_f = (__half*)(W + o); o += (size_t)4 * N;   // [N][8] fp16
  __half* Q2h_b = (__half*)(W + o); o += (size_t)4 * N;
  float* G_f   = W + o; o += (size_t)10 * N;              // [N][10] fp32
  float* G_b   = W + o; o += (size_t)10 * N;
  float* WpackA = W + o; o += 2000;
  float* WpackC = W + o; o += 1000;

  // binned scratch aliases the prop region (consumed by passC before nodeA
  // writes anything there); needs 4E words <= prop-region words (~102N).
  int2* binned_f = (int2*)(W + prop0);
  int2* binned_b = binned_f + E;

  const int NB2 = (2 * N + 255) / 256;
  const int NBd = 2 * ((2 * N + 255) / 256);   // dir-per-block grids
  const int NBn = (N + 63) / 64;

  // 1. packed weights
  prep_weights<<<8, 256, 0, stream>>>(Wz, Wr, Wh, WpackA, WpackC);

  // 2. CSR build
  hipMemsetAsync(bcnt_f, 0, 2 * MAXB * sizeof(int), stream);
  hist_kernel<<<512, 256, 0, stream>>>(ei, bcnt_f, bcnt_b, E);
  scanb_kernel<<<1, MAXB, 0, stream>>>(bcnt_f, bcnt_b, bbase_f, bbase_b,
                                       bcur_f, bcur_b, rs_f, rs_b,
                                       nbuck, N, E);
  passB_kernel<<<512, 512, 0, stream>>>(ei, ew, bcur_f, bcur_b,
                                        binned_f, binned_b, E);
  passC_kernel<<<dim3(nbuck, 2), 256, 0, stream>>>(
      binned_f, binned_b, bbase_f, bbase_b, adj_f, adj_b,
      rs_f, rs_b, inv_in, inv_out, N);
  wfout_kernel<<<1024, 256, 0, stream>>>(ei, ew, inv_out, wf_out, E);

  // 3. node phase A
  nodeA_kernel<<<NBn, 256, 0, stream>>>(x, W1, b1, W2, b2, bz, br, WpackA,
                                        WpackC, inv_out, inv_in,
                                        h1, accDz, accDr, PA_f, PA_b,
                                        accCx, N);

  // 4. fused propagation + gate phases
  p1_kernel<<<NBd, 256, 0, stream>>>(rs_f, rs_b, adj_f, adj_b, PA_f, PA_b,
                                     inv_out, inv_in, Q1_f, Q1_b, Q2_f, Q2_b, N);
  p2a_kernel<<<NBd, 256, 0, stream>>>(rs_f, rs_b, adj_f, adj_b, Q2_f, Q2_b,
                                      G_f, G_b, N);
  p2b_kernel<<<NB2, 256, 0, stream>>>(G_f, G_b, Q1_f, Q1_b, accDz, accDr,
                                      accCx, h1, bh, WpackC, inv_out, inv_in,
                                      Zg, accDh, PH_f, PH_b, N);
  p3_kernel<<<NBd, 256, 0, stream>>>(rs_f, rs_b, adj_f, adj_b, PH_f, PH_b,
                                     inv_out, inv_in, Q1h_f, Q1h_b,
                                     Q2h_f, Q2h_b, N);
  p4_kernel<<<NB2, 256, 0, stream>>>(rs_f, rs_b, adj_f, adj_b, Q2h_f, Q2h_b,
                                     Q1h_f, Q1h_b, accDh, Zg, h1, Wl, bl,
                                     y_out, N);
}